// Round 10
// baseline (1252.730 us; speedup 1.0000x reference)
//
#include <hip/hip_runtime.h>

typedef __bf16 bf16x8 __attribute__((ext_vector_type(8)));
typedef float  f32x4  __attribute__((ext_vector_type(4)));

__device__ __forceinline__ float b2f(unsigned short u) {
    union { unsigned int i; float f; } v; v.i = ((unsigned int)u) << 16; return v.f;
}
__device__ __forceinline__ unsigned short f2b(float f) {
    union { float f; unsigned int i; } v; v.f = f;
    unsigned int u = v.i;
    return (unsigned short)((u + 0x7fffu + ((u >> 16) & 1u)) >> 16);
}

// ---------------- tap table build ----------------
// invalid taps point at the zero row (index n) -> branch-free gathers in conv.
__global__ void table_init(int* __restrict__ tab, int n)
{
    int idx = blockIdx.x * blockDim.x + threadIdx.x;
    if (idx >= n * 27) return;
    tab[idx] = ((idx % 27) == 13) ? (idx / 27) : n;
}

__global__ void table_fill(int* __restrict__ tab, const int* __restrict__ map, int M, int n)
{
    int tid = blockIdx.x * blockDim.x + threadIdx.x;
    if (tid >= 26 * M) return;
    int j = tid / M, q = tid - j * M;
    int om = map[(26 + j) * M + q];
    if (om < n) {
        int k = (j < 13) ? j : j + 1;
        tab[om * 27 + k] = map[j * M + q];
    }
}

// ---------------- weight pack: W[j][k][cout] f32 -> B-fragment order bf16 ----------------
__global__ void pack_w(const float* __restrict__ W, unsigned short* __restrict__ P,
                       int total, int log2Cout, int log2KC)
{
    int tid = blockIdx.x * blockDim.x + threadIdx.x;
    if (tid >= total) return;
    int jj   = tid & 7;
    int cout = (tid >> 3) & ((1 << log2Cout) - 1);
    int rest = tid >> (3 + log2Cout);
    int quad = rest & 3;
    int kj   = rest >> 2;
    int kc   = kj & ((1 << log2KC) - 1);
    int j    = kj >> log2KC;
    int Cin  = (1 << log2KC) * 32;
    int Cout = 1 << log2Cout;
    P[tid] = f2b(W[((size_t)j * Cin + kc * 32 + quad * 8 + jj) * Cout + cout]);
}

__global__ void cast_bf16(const float* __restrict__ X, unsigned short* __restrict__ Y, int nElem)
{
    int tid = blockIdx.x * blockDim.x + threadIdx.x;
    if (tid < nElem) Y[tid] = f2b(X[tid]);
}

// ---------------- staged MFMA sparse conv (big levels) ----------------
// 256 threads = 4 waves; wave owns T*16 couts; block owns RT*16 rows.
// Depth-2 staging pipeline with STATIC register indexing (rule #20: runtime-
// indexed ext_vector arrays spill to scratch -- round 9's 326MB WRITE_SIZE):
// named sregA/sregB + 2x-unrolled tap loop. ds_write of tap j+1's data (loaded
// one full tap earlier) happens at the TOP of tap j -> its vmcnt wait sees
// loads aged ~a full tap (> L2 latency) -> no per-tap staging stall.
// Fused BN stats epilogue with 8 XCD-local replicas (bid&7 == XCD under swizzle).
template<int T, int KC, int RT, bool OUTBF16>
__global__ __launch_bounds__(256) void conv_mfma_st(
    const unsigned short* __restrict__ Xb, const unsigned short* __restrict__ P,
    const int* __restrict__ tab, void* __restrict__ OutV, float* __restrict__ St,
    int n, int nblk)
{
    constexpr int Cin = KC * 32, Cout = 64 * T;
    constexpr int ROWS = RT * 16;
    constexpr int STRIDE = KC * 32 + 8;   // shorts; odd multiple of 16B
    constexpr int CHUNKS = KC * 4;        // 16B chunks per row
    constexpr int RPR = 256 / CHUNKS;     // rows staged per round
    constexpr int NRD = ROWS / RPR;       // staging rounds
    __shared__ int tps[ROWS * 27];
    __shared__ unsigned short abuf[2][ROWS * STRIDE];

    const int t = threadIdx.x, lane = t & 63, wv = t >> 6;
    const int m = lane & 15, quad = lane >> 4;

    // bijective chunked XCD swizzle (keeps gather footprint in one XCD's L2)
    const int q = nblk >> 3, rr = nblk & 7;
    const int xcd = blockIdx.x & 7, pos = blockIdx.x >> 3;
    const int bswz = (xcd < rr) ? (xcd * (q + 1) + pos) : (rr * (q + 1) + (xcd - rr) * q + pos);
    const int r0 = bswz * ROWS;
    int rows = n - r0; if (rows > ROWS) rows = ROWS;

    for (int e = t; e < ROWS * 27; e += 256)
        tps[e] = (e < rows * 27) ? tab[(size_t)r0 * 27 + e] : n;
    __syncthreads();

    const int sr = t / CHUNKS;   // staging row-slot within a round
    const int sc = t % CHUNKS;   // staging 16B chunk

    f32x4 acc[RT][T];
    #pragma unroll
    for (int rt = 0; rt < RT; rt++)
        #pragma unroll
        for (int c = 0; c < T; c++) acc[rt][c] = f32x4{0.f, 0.f, 0.f, 0.f};

    uint4 sregA[NRD], sregB[NRD];   // named sets -> always statically indexed

    #define LOADTAP(REG, J)                                                              \
        _Pragma("unroll")                                                                \
        for (int rd = 0; rd < NRD; rd++) {                                               \
            int in = tps[(rd * RPR + sr) * 27 + (J)];                                    \
            REG[rd] = *reinterpret_cast<const uint4*>(Xb + (size_t)in * Cin + sc * 8);   \
        }
    #define WRITETAP(REG, BUF)                                                           \
        _Pragma("unroll")                                                                \
        for (int rd = 0; rd < NRD; rd++)                                                 \
            *reinterpret_cast<uint4*>(&abuf[BUF][(rd * RPR + sr) * STRIDE + sc * 8]) = REG[rd];
    #define COMPUTE(J, BUF)                                                              \
        _Pragma("unroll")                                                                \
        for (int kc = 0; kc < KC; kc++) {                                                \
            bf16x8 a[RT];                                                                \
            _Pragma("unroll")                                                            \
            for (int rt = 0; rt < RT; rt++)                                              \
                a[rt] = *reinterpret_cast<const bf16x8*>(&abuf[BUF][(rt * 16 + m) * STRIDE + kc * 32 + quad * 8]); \
            const unsigned short* bp = P + ((size_t)(((J) * KC + kc) * 4 + quad) * Cout + wv * (T * 16)) * 8;      \
            _Pragma("unroll")                                                            \
            for (int c = 0; c < T; c++) {                                                \
                bf16x8 b = *reinterpret_cast<const bf16x8*>(bp + (c * 16 + m) * 8);      \
                _Pragma("unroll")                                                        \
                for (int rt = 0; rt < RT; rt++)                                          \
                    acc[rt][c] = __builtin_amdgcn_mfma_f32_16x16x32_bf16(a[rt], b, acc[rt][c], 0, 0, 0); \
            }                                                                            \
        }

    // prologue: tap0 -> sregA -> abuf0; tap1 loads -> sregB
    LOADTAP(sregA, 0)
    WRITETAP(sregA, 0)
    LOADTAP(sregB, 1)
    __syncthreads();

    // 13 pairs handle taps 0..25; tap 26 is the tail (abuf0, no write/load).
    for (int jp = 0; jp < 13; jp++) {
        const int j = 2 * jp;
        // even tap j: abuf0 live; sregB holds tap j+1
        WRITETAP(sregB, 1)          // ds_write waits on loads aged one full tap
        LOADTAP(sregA, j + 2)       // j+2 <= 26
        COMPUTE(j, 0)
        __syncthreads();
        // odd tap j+1: abuf1 live; sregA holds tap j+2
        WRITETAP(sregA, 0)
        if (j + 3 < 27) { LOADTAP(sregB, j + 3) }
        COMPUTE(j + 1, 1)
        __syncthreads();
    }
    COMPUTE(26, 0)

    #undef LOADTAP
    #undef WRITETAP
    #undef COMPUTE

    #pragma unroll
    for (int c = 0; c < T; c++) {
        const int cout = (wv * T + c) * 16 + m;
        float s = 0.f, ss = 0.f;
        #pragma unroll
        for (int rt = 0; rt < RT; rt++) {
            #pragma unroll
            for (int reg = 0; reg < 4; reg++) {
                int r = rt * 16 + quad * 4 + reg;
                if (r < rows) {
                    float v = acc[rt][c][reg];
                    size_t off = (size_t)(r0 + r) * Cout + cout;
                    if (OUTBF16) {
                        unsigned short h = f2b(v);
                        ((unsigned short*)OutV)[off] = h;
                        v = b2f(h);
                    } else {
                        ((float*)OutV)[off] = v;
                    }
                    s += v; ss += v * v;
                }
            }
        }
        if (St) {
            s  += __shfl_xor(s, 16);  ss += __shfl_xor(ss, 16);
            s  += __shfl_xor(s, 32);  ss += __shfl_xor(ss, 32);
            if (quad == 0) {
                float* Sr = St + (size_t)(blockIdx.x & 7) * 2 * Cout;  // XCD-local replica
                atomicAdd(&Sr[cout], s);
                atomicAdd(&Sr[Cout + cout], ss);
            }
        }
    }
}

// ---------------- MFMA output-centric sparse conv (small levels) ----------------
template<int T, int RB, bool OUTBF16>
__global__ __launch_bounds__(256) void conv_mfma(
    const unsigned short* __restrict__ Xb, const unsigned short* __restrict__ P,
    const int* __restrict__ tab, void* __restrict__ OutV, int n, int Cin, int KC, int nblk)
{
    const int Cout = 64 * T;
    const int ROWS = RB * 16;
    __shared__ int tps[RB * 16 * 27];
    __shared__ int vld[27];
    const int t = threadIdx.x, lane = t & 63, wv = t >> 6;
    const int m = lane & 15, quad = lane >> 4;

    const int q = nblk >> 3, rr = nblk & 7;
    const int xcd = blockIdx.x & 7, pos = blockIdx.x >> 3;
    const int bswz = (xcd < rr) ? (xcd * (q + 1) + pos) : (rr * (q + 1) + (xcd - rr) * q + pos);
    const int r0 = bswz * ROWS;
    int rows = n - r0; if (rows > ROWS) rows = ROWS;

    for (int e = t; e < ROWS * 27; e += 256)
        tps[e] = (e < rows * 27) ? tab[(size_t)r0 * 27 + e] : n;
    __syncthreads();
    if constexpr (RB == 1) {
        if (t < 27) {
            int v = 0;
            for (int r = 0; r < 16; r++) v |= (tps[r * 27 + t] < n) ? 1 : 0;
            vld[t] = v;
        }
        __syncthreads();
    }

    f32x4 acc[RB][T];
    #pragma unroll
    for (int rt = 0; rt < RB; rt++)
        #pragma unroll
        for (int c = 0; c < T; c++) acc[rt][c] = f32x4{0.f, 0.f, 0.f, 0.f};

    const unsigned short* Xq = Xb + quad * 8;
    const unsigned short* Pq = P + ((size_t)quad * Cout + wv * (T * 16)) * 8;

    for (int j = 0; j < 27; j++) {
        if constexpr (RB == 1) {
            if (!vld[j]) continue;
        }
        int in[RB];
        #pragma unroll
        for (int rt = 0; rt < RB; rt++) in[rt] = tps[(rt * 16 + m) * 27 + j];
        for (int kc = 0; kc < KC; kc++) {
            bf16x8 a[RB];
            #pragma unroll
            for (int rt = 0; rt < RB; rt++)
                a[rt] = *reinterpret_cast<const bf16x8*>(Xq + (size_t)in[rt] * Cin + kc * 32);
            const unsigned short* bp = Pq + (size_t)((j * KC + kc) * 4) * Cout * 8;
            #pragma unroll
            for (int c = 0; c < T; c++) {
                bf16x8 b = *reinterpret_cast<const bf16x8*>(bp + (c * 16 + m) * 8);
                #pragma unroll
                for (int rt = 0; rt < RB; rt++)
                    acc[rt][c] = __builtin_amdgcn_mfma_f32_16x16x32_bf16(a[rt], b, acc[rt][c], 0, 0, 0);
            }
        }
    }

    #pragma unroll
    for (int c = 0; c < T; c++) {
        int cout = (wv * T + c) * 16 + m;
        #pragma unroll
        for (int rt = 0; rt < RB; rt++) {
            #pragma unroll
            for (int reg = 0; reg < 4; reg++) {
                int r = rt * 16 + quad * 4 + reg;
                if (r < rows) {
                    size_t off = (size_t)(r0 + r) * Cout + cout;
                    if (OUTBF16) ((unsigned short*)OutV)[off] = f2b(acc[rt][c][reg]);
                    else         ((float*)OutV)[off] = acc[rt][c][reg];
                }
            }
        }
    }
}

// ---------------- MFMA transpose conv: 8 children per row, A held in regs ----------------
template<int KC, int T>
__global__ __launch_bounds__(256) void tconv_mfma(
    const unsigned short* __restrict__ Xb, const unsigned short* __restrict__ P,
    unsigned short* __restrict__ Out, int n)
{
    const int Cin = KC * 32, Cout = 64 * T;
    const int t = threadIdx.x, lane = t & 63, wv = t >> 6;
    const int m = lane & 15, quad = lane >> 4;
    const int r0 = blockIdx.x * 16;
    int rows = n - r0; if (rows > 16) rows = 16;

    bf16x8 a[KC];
    #pragma unroll
    for (int kc = 0; kc < KC; kc++) {
        a[kc] = bf16x8{};
        if (m < rows)
            a[kc] = *reinterpret_cast<const bf16x8*>(Xb + (size_t)(r0 + m) * Cin + kc * 32 + quad * 8);
    }

    for (int o = 0; o < 8; o++) {
        f32x4 acc[T];
        #pragma unroll
        for (int c = 0; c < T; c++) acc[c] = f32x4{0.f, 0.f, 0.f, 0.f};
        #pragma unroll
        for (int kc = 0; kc < KC; kc++) {
            const unsigned short* bp = P + ((size_t)((o * KC + kc) * 4 + quad) * Cout + wv * (T * 16)) * 8;
            #pragma unroll
            for (int c = 0; c < T; c++) {
                bf16x8 b = *reinterpret_cast<const bf16x8*>(bp + (c * 16 + m) * 8);
                acc[c] = __builtin_amdgcn_mfma_f32_16x16x32_bf16(a[kc], b, acc[c], 0, 0, 0);
            }
        }
        #pragma unroll
        for (int c = 0; c < T; c++) {
            int cout = (wv * T + c) * 16 + m;
            #pragma unroll
            for (int reg = 0; reg < 4; reg++) {
                int r = quad * 4 + reg;
                if (r < rows)
                    Out[((size_t)o * n + r0 + r) * Cout + cout] = f2b(acc[c][reg]);
            }
        }
    }
}

// ---------------- misc ----------------
__global__ void scatter_add_f32(float* __restrict__ dst, const float* __restrict__ src,
                                const int* __restrict__ idx, long total, int C)
{
    long tid = (long)blockIdx.x * blockDim.x + threadIdx.x;
    if (tid >= total) return;
    long r = tid / C;
    int  c = (int)(tid - r * C);
    dst[(long)idx[r] * C + c] += src[tid];
}

__global__ void scatter_add_b16(float* __restrict__ dst, const unsigned short* __restrict__ src,
                                const int* __restrict__ idx, long total, int C)
{
    long tid = (long)blockIdx.x * blockDim.x + threadIdx.x;
    if (tid >= total) return;
    long r = tid / C;
    int  c = (int)(tid - r * C);
    dst[(long)idx[r] * C + c] += b2f(src[tid]);
}

template<bool BF16>
__global__ void bn_stats_k(const void* __restrict__ Xv, float* __restrict__ stats,
                           int n, int C, int rowsPerBlock)
{
    const int t = threadIdx.x;
    const int c = t & (C - 1);
    const int sub = t / C;
    const int nsub = 256 / C;
    int r0 = blockIdx.x * rowsPerBlock + sub;
    int r1 = blockIdx.x * rowsPerBlock + rowsPerBlock;
    if (r1 > n) r1 = n;
    float s = 0.f, ss = 0.f;
    for (int r = r0; r < r1; r += nsub) {
        float v = BF16 ? b2f(((const unsigned short*)Xv)[(long)r * C + c])
                       : ((const float*)Xv)[(long)r * C + c];
        s += v; ss += v * v;
    }
    __shared__ float bs[256];
    __shared__ float bq[256];
    bs[t] = s; bq[t] = ss;
    __syncthreads();
    if (sub == 0) {
        for (int k = 1; k < nsub; k++) { s += bs[k * C + c]; ss += bq[k * C + c]; }
        atomicAdd(&stats[c], s);
        atomicAdd(&stats[C + c], ss);
    }
}

// nrep: number of stats replicas to sum (fused convs write 8 XCD-local replicas)
template<bool BF16>
__global__ void bn_apply_k(void* __restrict__ Xv, const float* __restrict__ stats,
                           const float* __restrict__ gb, long total, int C, float invn, int nrep)
{
    long tid = (long)blockIdx.x * blockDim.x + threadIdx.x;
    if (tid >= total) return;
    int c = (int)(tid & (C - 1));
    float sm = 0.f, sq = 0.f;
    for (int r = 0; r < nrep; r++) {
        sm += stats[r * 2 * C + c];
        sq += stats[r * 2 * C + C + c];
    }
    float mu  = sm * invn;
    float var = sq * invn - mu * mu;
    float sc  = gb[c] * rsqrtf(var + 1e-5f);
    float x   = BF16 ? b2f(((unsigned short*)Xv)[tid]) : ((float*)Xv)[tid];
    float v   = (x - mu) * sc + gb[C + c];
    v = (v > 0.f) ? v : expm1f(v);
    if (BF16) ((unsigned short*)Xv)[tid] = f2b(v);
    else      ((float*)Xv)[tid] = v;
}

extern "C" void kernel_launch(void* const* d_in, const int* in_sizes, int n_in,
                              void* d_out, int out_size, void* d_ws, size_t ws_size,
                              hipStream_t stream)
{
    const float* feats0  = (const float*)d_in[0];
    const float* feats1  = (const float*)d_in[1];
    const float* feats2  = (const float*)d_in[2];
    const float* w_out0  = (const float*)d_in[3];
    const float* w_out1  = (const float*)d_in[4];
    const float* w_out2  = (const float*)d_in[5];
    const float* wt2     = (const float*)d_in[6];
    const float* wu2     = (const float*)d_in[7];
    const float* wt1     = (const float*)d_in[8];
    const float* wu1     = (const float*)d_in[9];
    const float* bn_out0 = (const float*)d_in[10];
    const float* bn_out1 = (const float*)d_in[11];
    const float* bn_out2 = (const float*)d_in[12];
    const float* bn_up2a = (const float*)d_in[13];
    const float* bn_up2b = (const float*)d_in[14];
    const float* bn_up1a = (const float*)d_in[15];
    const float* bn_up1b = (const float*)d_in[16];
    const int* m_c2 = (const int*)d_in[19];
    const int* m_g2 = (const int*)d_in[20];
    const int* m_u1 = (const int*)d_in[21];
    const int* m_g1 = (const int*)d_in[22];
    const int* m_u0 = (const int*)d_in[23];
    const int* lat1 = (const int*)d_in[24];
    const int* up1  = (const int*)d_in[25];
    const int* lat0 = (const int*)d_in[26];
    const int* up0  = (const int*)d_in[27];

    const int N0  = in_sizes[0] / 64;
    const int N1  = in_sizes[1] / 128;
    const int N2  = in_sizes[2] / 256;
    const int U1  = in_sizes[17] / 128;
    const int U0  = in_sizes[18] / 64;
    const int G2n = in_sizes[25];        // 8*N2
    const int G1n = in_sizes[27];        // 8*U1
    const int Mc2 = in_sizes[19] / 52;
    const int Mg2 = in_sizes[20] / 52;
    const int Mu1 = in_sizes[21] / 52;
    const int Mg1 = in_sizes[22] / 52;
    const int Mu0 = in_sizes[23] / 52;

    float* out0 = (float*)d_out;
    float* out1 = out0 + (size_t)U0 * 128;
    float* out2 = out1 + (size_t)U1 * 128;

    // ---- workspace (256B-aligned bump allocator) ----
    char* wp = (char*)d_ws;
    auto alloc = [&](size_t bytes) -> char* {
        char* r = wp; wp += (bytes + 255) & ~(size_t)255; return r;
    };
    float*          x0   = (float*)alloc((size_t)U0 * 64 * 4);   // tab_g1 aliases (built before x0 written)
    unsigned short* t1   = (unsigned short*)alloc((size_t)(G1n + 1) * 64 * 2);  // tab_u0 aliases t1|t1c (both dead)
    unsigned short* t1c  = (unsigned short*)alloc((size_t)(G1n + 1) * 64 * 2);
    unsigned short* t2   = (unsigned short*)alloc((size_t)(G2n + 1) * 128 * 2);
    unsigned short* t2c  = (unsigned short*)alloc((size_t)(G2n + 1) * 128 * 2);
    float*          x1   = (float*)alloc((size_t)U1 * 128 * 4);
    unsigned short* x1b  = (unsigned short*)alloc((size_t)(U1 + 1) * 128 * 2);
    unsigned short* x0b  = (unsigned short*)alloc((size_t)(U0 + 1) * 64 * 2);
    unsigned short* f2bb = (unsigned short*)alloc((size_t)(N2 + 1) * 256 * 2);
    unsigned short* pc2  = (unsigned short*)alloc((size_t)27 * 256 * 128 * 2);
    unsigned short* pt2  = (unsigned short*)alloc((size_t)8  * 256 * 128 * 2);
    unsigned short* pg2  = (unsigned short*)alloc((size_t)27 * 128 * 128 * 2);
    unsigned short* pu1  = (unsigned short*)alloc((size_t)27 * 128 * 128 * 2);
    unsigned short* pt1  = (unsigned short*)alloc((size_t)8  * 128 * 64  * 2);
    unsigned short* pg1  = (unsigned short*)alloc((size_t)27 * 64  * 64  * 2);
    unsigned short* pu0  = (unsigned short*)alloc((size_t)27 * 64  * 128 * 2);
    int maxSmall = (U1 > G2n) ? U1 : G2n;
    int*   smallTab = (int*)alloc((size_t)maxSmall * 27 * 4);
    float* stats    = (float*)alloc(8 * 2 * 128 * 4);   // 8 replicas x (sum,sumsq) x up to 128 ch
    int* tab_g1 = (int*)x0;   // G1n*27*4  <= U0*64*4 since U0 >= G1n
    int* tab_u0 = (int*)t1;   // U0*27*4   <= t1+t1c region (both dead by then)

    // ---- zero rows for branch-free gathers (index n of every conv input) ----
    hipMemsetAsync(f2bb + (size_t)N2  * 256, 0, 256 * 2, stream);
    hipMemsetAsync(t2   + (size_t)G2n * 128, 0, 128 * 2, stream);
    hipMemsetAsync(x1b  + (size_t)U1  * 128, 0, 128 * 2, stream);
    hipMemsetAsync(t1   + (size_t)G1n * 64,  0, 64  * 2, stream);
    hipMemsetAsync(x0b  + (size_t)U0  * 64,  0, 64  * 2, stream);

    auto packW = [&](const float* W, unsigned short* P, int taps, int l2co, int l2kc) {
        int total = taps * ((1 << l2kc) * 32) * (1 << l2co);
        pack_w<<<dim3((total + 255) / 256), dim3(256), 0, stream>>>(W, P, total, l2co, l2kc);
    };
    auto cast = [&](const float* X, unsigned short* Y, long nElem) {
        cast_bf16<<<dim3((int)((nElem + 255) / 256)), dim3(256), 0, stream>>>(X, Y, (int)nElem);
    };
    auto buildTab = [&](int* tab, const int* map, int M, int n) {
        table_init<<<dim3((n * 27 + 255) / 256), dim3(256), 0, stream>>>(tab, n);
        table_fill<<<dim3((26 * M + 255) / 256), dim3(256), 0, stream>>>(tab, map, M, n);
    };
    auto conv = [&](const unsigned short* Xb, const unsigned short* P, const int* tab,
                    void* Out, int n, int Cin, int Cout, bool outbf16, float* st) {
        int KC = Cin / 32;
        if (n >= 12000) {
            if (Cout == 128 && KC == 2) {
                int nblk = (n + 63) / 64;
                dim3 g(nblk), b(256);
                if (outbf16) conv_mfma_st<2, 2, 4, true ><<<g, b, 0, stream>>>(Xb, P, tab, Out, st, n, nblk);
                else         conv_mfma_st<2, 2, 4, false><<<g, b, 0, stream>>>(Xb, P, tab, Out, st, n, nblk);
                return;
            }
            if (Cout == 64 && KC == 2) {
                int nblk = (n + 63) / 64;
                dim3 g(nblk), b(256);
                if (outbf16) conv_mfma_st<1, 2, 4, true ><<<g, b, 0, stream>>>(Xb, P, tab, Out, st, n, nblk);
                else         conv_mfma_st<1, 2, 4, false><<<g, b, 0, stream>>>(Xb, P, tab, Out, st, n, nblk);
                return;
            }
            if (Cout == 128 && KC == 4) {
                int nblk = (n + 31) / 32;   // RT=2: grid 2x (was < #CUs at RT=4)
                dim3 g(nblk), b(256);
                if (outbf16) conv_mfma_st<2, 4, 2, true ><<<g, b, 0, stream>>>(Xb, P, tab, Out, st, n, nblk);
                else         conv_mfma_st<2, 4, 2, false><<<g, b, 0, stream>>>(Xb, P, tab, Out, st, n, nblk);
                return;
            }
        }
        int RB = (n >= 12000) ? 2 : 1;
        int nblk = (n + RB * 16 - 1) / (RB * 16);
        dim3 g(nblk), b(256);
        #define CONV_CASE(T_, RB_)                                                                        \
            if (Cout == 64 * T_ && RB == RB_) {                                                           \
                if (outbf16) conv_mfma<T_, RB_, true ><<<g, b, 0, stream>>>(Xb, P, tab, Out, n, Cin, KC, nblk); \
                else         conv_mfma<T_, RB_, false><<<g, b, 0, stream>>>(Xb, P, tab, Out, n, Cin, KC, nblk); \
                return;                                                                                   \
            }
        CONV_CASE(2, 2) CONV_CASE(2, 1)
        CONV_CASE(1, 2) CONV_CASE(1, 1)
        #undef CONV_CASE
    };
    auto bnapply = [&](void* X, const float* gb, int n, int C, bool bf16, int nrep) {
        long total = (long)n * C;
        if (bf16) bn_apply_k<true ><<<dim3((int)((total + 255) / 256)), dim3(256), 0, stream>>>(X, stats, gb, total, C, 1.0f / n, nrep);
        else      bn_apply_k<false><<<dim3((int)((total + 255) / 256)), dim3(256), 0, stream>>>(X, stats, gb, total, C, 1.0f / n, nrep);
    };
    auto bnelu = [&](void* X, const float* gb, int n, int C, bool bf16) {
        hipMemsetAsync(stats, 0, 2 * C * sizeof(float), stream);
        const int rpb = 512;
        if (bf16) bn_stats_k<true ><<<dim3((n + rpb - 1) / rpb), dim3(256), 0, stream>>>(X, stats, n, C, rpb);
        else      bn_stats_k<false><<<dim3((n + rpb - 1) / rpb), dim3(256), 0, stream>>>(X, stats, n, C, rpb);
        bnapply(X, gb, n, C, bf16, 1);
    };

    // ---- weight packs + input cast ----
    cast(feats2, f2bb, (long)N2 * 256);
    packW(w_out2, pc2, 27, 7, 3);
    packW(wt2,    pt2,  8, 7, 3);
    packW(wu2,    pg2, 27, 7, 2);
    packW(w_out1, pu1, 27, 7, 2);
    packW(wt1,    pt1,  8, 6, 2);
    packW(wu1,    pg1, 27, 6, 1);
    packW(w_out0, pu0, 27, 7, 1);

    // ---- level 2 ----
    buildTab(smallTab, m_c2, Mc2, N2);
    conv(f2bb, pc2, smallTab, out2, N2, 256, 128, false, nullptr);
    bnelu(out2, bn_out2, N2, 128, false);
    tconv_mfma<8, 2><<<dim3((N2 + 15) / 16), dim3(256), 0, stream>>>(f2bb, pt2, t2, N2);
    bnelu(t2, bn_up2a, G2n, 128, true);
    buildTab(smallTab, m_g2, Mg2, G2n);
    conv(t2, pg2, smallTab, t2c, G2n, 128, 128, true, nullptr);
    bnelu(t2c, bn_up2b, G2n, 128, true);

    // ---- level 1 ----
    hipMemsetAsync(x1, 0, (size_t)U1 * 128 * sizeof(float), stream);
    {
        long tot = (long)N1 * 128;
        scatter_add_f32<<<dim3((int)((tot + 255) / 256)), dim3(256), 0, stream>>>(x1, feats1, lat1, tot, 128);
        tot = (long)G2n * 128;
        scatter_add_b16<<<dim3((int)((tot + 255) / 256)), dim3(256), 0, stream>>>(x1, t2c, up1, tot, 128);
    }
    cast(x1, x1b, (long)U1 * 128);
    buildTab(smallTab, m_u1, Mu1, U1);
    hipMemsetAsync(stats, 0, 8 * 2 * 128 * sizeof(float), stream);
    conv(x1b, pu1, smallTab, out1, U1, 128, 128, false, stats);
    bnapply(out1, bn_out1, U1, 128, false, 8);
    tconv_mfma<4, 1><<<dim3((U1 + 15) / 16), dim3(256), 0, stream>>>(x1b, pt1, t1, U1);
    bnelu(t1, bn_up1a, G1n, 64, true);
    buildTab(tab_g1, m_g1, Mg1, G1n);
    hipMemsetAsync(stats, 0, 8 * 2 * 64 * sizeof(float), stream);
    conv(t1, pg1, tab_g1, t1c, G1n, 64, 64, true, stats);
    bnapply(t1c, bn_up1b, G1n, 64, true, 8);

    // ---- level 0 ----
    hipMemsetAsync(x0, 0, (size_t)U0 * 64 * sizeof(float), stream);
    {
        long tot = (long)N0 * 64;
        scatter_add_f32<<<dim3((int)((tot + 255) / 256)), dim3(256), 0, stream>>>(x0, feats0, lat0, tot, 64);
        tot = (long)G1n * 64;
        scatter_add_b16<<<dim3((int)((tot + 255) / 256)), dim3(256), 0, stream>>>(x0, t1c, up0, tot, 64);
    }
    buildTab(tab_u0, m_u0, Mu0, U0);
    cast(x0, x0b, (long)U0 * 64);
    hipMemsetAsync(stats, 0, 8 * 2 * 128 * sizeof(float), stream);
    conv(x0b, pu0, tab_u0, out0, U0, 64, 128, false, stats);
    bnapply(out0, bn_out0, U0, 128, false, 8);
}

// Round 11
// 1082.634 us; speedup vs baseline: 1.1571x; 1.1571x over previous
//
#include <hip/hip_runtime.h>

typedef __bf16 bf16x8 __attribute__((ext_vector_type(8)));
typedef float  f32x4  __attribute__((ext_vector_type(4)));

__device__ __forceinline__ float b2f(unsigned short u) {
    union { unsigned int i; float f; } v; v.i = ((unsigned int)u) << 16; return v.f;
}
__device__ __forceinline__ unsigned short f2b(float f) {
    union { float f; unsigned int i; } v; v.f = f;
    unsigned int u = v.i;
    return (unsigned short)((u + 0x7fffu + ((u >> 16) & 1u)) >> 16);
}

// ---------------- tap table build ----------------
// invalid taps point at the zero row (index n) -> branch-free gathers in conv.
__global__ void table_init(int* __restrict__ tab, int n)
{
    int idx = blockIdx.x * blockDim.x + threadIdx.x;
    if (idx >= n * 27) return;
    tab[idx] = ((idx % 27) == 13) ? (idx / 27) : n;
}

__global__ void table_fill(int* __restrict__ tab, const int* __restrict__ map, int M, int n)
{
    int tid = blockIdx.x * blockDim.x + threadIdx.x;
    if (tid >= 26 * M) return;
    int j = tid / M, q = tid - j * M;
    int om = map[(26 + j) * M + q];
    if (om < n) {
        int k = (j < 13) ? j : j + 1;
        tab[om * 27 + k] = map[j * M + q];
    }
}

// ---------------- weight pack: W[j][k][cout] f32 -> B-fragment order bf16 ----------------
__global__ void pack_w(const float* __restrict__ W, unsigned short* __restrict__ P,
                       int total, int log2Cout, int log2KC)
{
    int tid = blockIdx.x * blockDim.x + threadIdx.x;
    if (tid >= total) return;
    int jj   = tid & 7;
    int cout = (tid >> 3) & ((1 << log2Cout) - 1);
    int rest = tid >> (3 + log2Cout);
    int quad = rest & 3;
    int kj   = rest >> 2;
    int kc   = kj & ((1 << log2KC) - 1);
    int j    = kj >> log2KC;
    int Cin  = (1 << log2KC) * 32;
    int Cout = 1 << log2Cout;
    P[tid] = f2b(W[((size_t)j * Cin + kc * 32 + quad * 8 + jj) * Cout + cout]);
}

__global__ void cast_bf16(const float* __restrict__ X, unsigned short* __restrict__ Y, int nElem)
{
    int tid = blockIdx.x * blockDim.x + threadIdx.x;
    if (tid < nElem) Y[tid] = f2b(X[tid]);
}

// ---------------- staged MFMA sparse conv (big levels) ----------------
// 256 threads = 4 waves; wave owns T*16 couts; block owns RT*16 rows.
// Staging via __builtin_amdgcn_global_load_lds: async global->LDS DMA, ZERO
// VGPR footprint (rounds 9/10 proved register-held prefetch spills to scratch
// in this pressure regime: 326-460MB scratch WRITE). LDS is linear (DMA dest =
// wave-uniform base + lane*16); bank conflicts on the ds_read side are handled
// by pre-swizzling the global SOURCE (rule #21): chunk ck of row r lives at
// slot ck ^ (r & (CHUNKS-1)), and the read applies the same XOR -> bank index
// depends only on slot -> 2-way aliasing (free). Single-depth double buffer:
// DMA for tap j+1 issues before MFMA(j); the barrier's vmcnt drain lands after
// the MFMA phase. Fused BN stats epilogue with 8 XCD-local replicas.
template<int T, int KC, int RT, bool OUTBF16>
__global__ __launch_bounds__(256) void conv_mfma_st(
    const unsigned short* __restrict__ Xb, const unsigned short* __restrict__ P,
    const int* __restrict__ tab, void* __restrict__ OutV, float* __restrict__ St,
    int n, int nblk)
{
    constexpr int Cin = KC * 32, Cout = 64 * T;
    constexpr int ROWS = RT * 16;
    constexpr int CHUNKS = KC * 4;          // 16B chunks per row
    constexpr int RSH = KC * 32;            // shorts per row (linear, no padding)
    constexpr int TOTALC = ROWS * CHUNKS;   // 16B chunks per tap (512 for all cases)
    constexpr int NQ = TOTALC / 256;        // DMA issues per thread-slot
    __shared__ int tps[ROWS * 27];
    __shared__ unsigned short abuf[2][ROWS * RSH];

    const int t = threadIdx.x, lane = t & 63, wv = t >> 6;
    const int m = lane & 15, quad = lane >> 4;

    // bijective chunked XCD swizzle (keeps gather footprint in one XCD's L2)
    const int q = nblk >> 3, rr = nblk & 7;
    const int xcd = blockIdx.x & 7, pos = blockIdx.x >> 3;
    const int bswz = (xcd < rr) ? (xcd * (q + 1) + pos) : (rr * (q + 1) + (xcd - rr) * q + pos);
    const int r0 = bswz * ROWS;
    int rows = n - r0; if (rows > ROWS) rows = ROWS;

    for (int e = t; e < ROWS * 27; e += 256)
        tps[e] = (e < rows * 27) ? tab[(size_t)r0 * 27 + e] : n;
    __syncthreads();

    f32x4 acc[RT][T];
    #pragma unroll
    for (int rt = 0; rt < RT; rt++)
        #pragma unroll
        for (int c = 0; c < T; c++) acc[rt][c] = f32x4{0.f, 0.f, 0.f, 0.f};

    // async stage of tap J into abuf[buf]: per wave, NQ x 64 lanes x 16B DMA.
    // dest is linear (chunk ci at shorts ci*8); source chunk is XOR-swizzled.
    auto stage = [&](int J, int buf) {
        #pragma unroll
        for (int qq = 0; qq < NQ; qq++) {
            const int ci    = qq * 256 + wv * 64 + lane;
            const int row   = ci / CHUNKS;
            const int dslot = ci & (CHUNKS - 1);
            const int sc    = dslot ^ (row & (CHUNKS - 1));
            const int in    = tps[row * 27 + J];
            const unsigned short* gp = Xb + (size_t)in * Cin + sc * 8;
            unsigned short* lp = &abuf[buf][(size_t)(qq * 256 + wv * 64) * 8];
            __builtin_amdgcn_global_load_lds(
                (const __attribute__((address_space(1))) void*)gp,
                (__attribute__((address_space(3))) void*)lp, 16, 0, 0);
        }
    };

    stage(0, 0);
    __syncthreads();   // drains vmcnt -> tap 0 resident

    for (int j = 0; j < 27; j++) {
        const int cur = j & 1;
        if (j + 1 < 27) stage(j + 1, cur ^ 1);   // DMA overlaps the MFMAs below
        #pragma unroll
        for (int kc = 0; kc < KC; kc++) {
            const int swz = ((kc * 4 + quad) ^ (m & (CHUNKS - 1))) * 8;
            bf16x8 a[RT];
            #pragma unroll
            for (int rt = 0; rt < RT; rt++)
                a[rt] = *reinterpret_cast<const bf16x8*>(&abuf[cur][(rt * 16 + m) * RSH + swz]);
            const unsigned short* bp = P + ((size_t)((j * KC + kc) * 4 + quad) * Cout + wv * (T * 16)) * 8;
            #pragma unroll
            for (int c = 0; c < T; c++) {
                bf16x8 b = *reinterpret_cast<const bf16x8*>(bp + (c * 16 + m) * 8);
                #pragma unroll
                for (int rt = 0; rt < RT; rt++)
                    acc[rt][c] = __builtin_amdgcn_mfma_f32_16x16x32_bf16(a[rt], b, acc[rt][c], 0, 0, 0);
            }
        }
        __syncthreads();   // vmcnt drain: tap j+1 data resident for next iter
    }

    #pragma unroll
    for (int c = 0; c < T; c++) {
        const int cout = (wv * T + c) * 16 + m;
        float s = 0.f, ss = 0.f;
        #pragma unroll
        for (int rt = 0; rt < RT; rt++) {
            #pragma unroll
            for (int reg = 0; reg < 4; reg++) {
                int r = rt * 16 + quad * 4 + reg;
                if (r < rows) {
                    float v = acc[rt][c][reg];
                    size_t off = (size_t)(r0 + r) * Cout + cout;
                    if (OUTBF16) {
                        unsigned short h = f2b(v);
                        ((unsigned short*)OutV)[off] = h;
                        v = b2f(h);
                    } else {
                        ((float*)OutV)[off] = v;
                    }
                    s += v; ss += v * v;
                }
            }
        }
        if (St) {
            s  += __shfl_xor(s, 16);  ss += __shfl_xor(ss, 16);
            s  += __shfl_xor(s, 32);  ss += __shfl_xor(ss, 32);
            if (quad == 0) {
                float* Sr = St + (size_t)(blockIdx.x & 7) * 2 * Cout;  // XCD-local replica
                atomicAdd(&Sr[cout], s);
                atomicAdd(&Sr[Cout + cout], ss);
            }
        }
    }
}

// ---------------- MFMA output-centric sparse conv (small levels) ----------------
template<int T, int RB, bool OUTBF16>
__global__ __launch_bounds__(256) void conv_mfma(
    const unsigned short* __restrict__ Xb, const unsigned short* __restrict__ P,
    const int* __restrict__ tab, void* __restrict__ OutV, int n, int Cin, int KC, int nblk)
{
    const int Cout = 64 * T;
    const int ROWS = RB * 16;
    __shared__ int tps[RB * 16 * 27];
    __shared__ int vld[27];
    const int t = threadIdx.x, lane = t & 63, wv = t >> 6;
    const int m = lane & 15, quad = lane >> 4;

    const int q = nblk >> 3, rr = nblk & 7;
    const int xcd = blockIdx.x & 7, pos = blockIdx.x >> 3;
    const int bswz = (xcd < rr) ? (xcd * (q + 1) + pos) : (rr * (q + 1) + (xcd - rr) * q + pos);
    const int r0 = bswz * ROWS;
    int rows = n - r0; if (rows > ROWS) rows = ROWS;

    for (int e = t; e < ROWS * 27; e += 256)
        tps[e] = (e < rows * 27) ? tab[(size_t)r0 * 27 + e] : n;
    __syncthreads();
    if constexpr (RB == 1) {
        if (t < 27) {
            int v = 0;
            for (int r = 0; r < 16; r++) v |= (tps[r * 27 + t] < n) ? 1 : 0;
            vld[t] = v;
        }
        __syncthreads();
    }

    f32x4 acc[RB][T];
    #pragma unroll
    for (int rt = 0; rt < RB; rt++)
        #pragma unroll
        for (int c = 0; c < T; c++) acc[rt][c] = f32x4{0.f, 0.f, 0.f, 0.f};

    const unsigned short* Xq = Xb + quad * 8;
    const unsigned short* Pq = P + ((size_t)quad * Cout + wv * (T * 16)) * 8;

    for (int j = 0; j < 27; j++) {
        if constexpr (RB == 1) {
            if (!vld[j]) continue;
        }
        int in[RB];
        #pragma unroll
        for (int rt = 0; rt < RB; rt++) in[rt] = tps[(rt * 16 + m) * 27 + j];
        for (int kc = 0; kc < KC; kc++) {
            bf16x8 a[RB];
            #pragma unroll
            for (int rt = 0; rt < RB; rt++)
                a[rt] = *reinterpret_cast<const bf16x8*>(Xq + (size_t)in[rt] * Cin + kc * 32);
            const unsigned short* bp = Pq + (size_t)((j * KC + kc) * 4) * Cout * 8;
            #pragma unroll
            for (int c = 0; c < T; c++) {
                bf16x8 b = *reinterpret_cast<const bf16x8*>(bp + (c * 16 + m) * 8);
                #pragma unroll
                for (int rt = 0; rt < RB; rt++)
                    acc[rt][c] = __builtin_amdgcn_mfma_f32_16x16x32_bf16(a[rt], b, acc[rt][c], 0, 0, 0);
            }
        }
    }

    #pragma unroll
    for (int c = 0; c < T; c++) {
        int cout = (wv * T + c) * 16 + m;
        #pragma unroll
        for (int rt = 0; rt < RB; rt++) {
            #pragma unroll
            for (int reg = 0; reg < 4; reg++) {
                int r = rt * 16 + quad * 4 + reg;
                if (r < rows) {
                    size_t off = (size_t)(r0 + r) * Cout + cout;
                    if (OUTBF16) ((unsigned short*)OutV)[off] = f2b(acc[rt][c][reg]);
                    else         ((float*)OutV)[off] = acc[rt][c][reg];
                }
            }
        }
    }
}

// ---------------- MFMA transpose conv: 8 children per row, A held in regs ----------------
template<int KC, int T>
__global__ __launch_bounds__(256) void tconv_mfma(
    const unsigned short* __restrict__ Xb, const unsigned short* __restrict__ P,
    unsigned short* __restrict__ Out, int n)
{
    const int Cin = KC * 32, Cout = 64 * T;
    const int t = threadIdx.x, lane = t & 63, wv = t >> 6;
    const int m = lane & 15, quad = lane >> 4;
    const int r0 = blockIdx.x * 16;
    int rows = n - r0; if (rows > 16) rows = 16;

    bf16x8 a[KC];
    #pragma unroll
    for (int kc = 0; kc < KC; kc++) {
        a[kc] = bf16x8{};
        if (m < rows)
            a[kc] = *reinterpret_cast<const bf16x8*>(Xb + (size_t)(r0 + m) * Cin + kc * 32 + quad * 8);
    }

    for (int o = 0; o < 8; o++) {
        f32x4 acc[T];
        #pragma unroll
        for (int c = 0; c < T; c++) acc[c] = f32x4{0.f, 0.f, 0.f, 0.f};
        #pragma unroll
        for (int kc = 0; kc < KC; kc++) {
            const unsigned short* bp = P + ((size_t)((o * KC + kc) * 4 + quad) * Cout + wv * (T * 16)) * 8;
            #pragma unroll
            for (int c = 0; c < T; c++) {
                bf16x8 b = *reinterpret_cast<const bf16x8*>(bp + (c * 16 + m) * 8);
                acc[c] = __builtin_amdgcn_mfma_f32_16x16x32_bf16(a[kc], b, acc[c], 0, 0, 0);
            }
        }
        #pragma unroll
        for (int c = 0; c < T; c++) {
            int cout = (wv * T + c) * 16 + m;
            #pragma unroll
            for (int reg = 0; reg < 4; reg++) {
                int r = quad * 4 + reg;
                if (r < rows)
                    Out[((size_t)o * n + r0 + r) * Cout + cout] = f2b(acc[c][reg]);
            }
        }
    }
}

// ---------------- misc ----------------
__global__ void scatter_add_f32(float* __restrict__ dst, const float* __restrict__ src,
                                const int* __restrict__ idx, long total, int C)
{
    long tid = (long)blockIdx.x * blockDim.x + threadIdx.x;
    if (tid >= total) return;
    long r = tid / C;
    int  c = (int)(tid - r * C);
    dst[(long)idx[r] * C + c] += src[tid];
}

__global__ void scatter_add_b16(float* __restrict__ dst, const unsigned short* __restrict__ src,
                                const int* __restrict__ idx, long total, int C)
{
    long tid = (long)blockIdx.x * blockDim.x + threadIdx.x;
    if (tid >= total) return;
    long r = tid / C;
    int  c = (int)(tid - r * C);
    dst[(long)idx[r] * C + c] += b2f(src[tid]);
}

template<bool BF16>
__global__ void bn_stats_k(const void* __restrict__ Xv, float* __restrict__ stats,
                           int n, int C, int rowsPerBlock)
{
    const int t = threadIdx.x;
    const int c = t & (C - 1);
    const int sub = t / C;
    const int nsub = 256 / C;
    int r0 = blockIdx.x * rowsPerBlock + sub;
    int r1 = blockIdx.x * rowsPerBlock + rowsPerBlock;
    if (r1 > n) r1 = n;
    float s = 0.f, ss = 0.f;
    for (int r = r0; r < r1; r += nsub) {
        float v = BF16 ? b2f(((const unsigned short*)Xv)[(long)r * C + c])
                       : ((const float*)Xv)[(long)r * C + c];
        s += v; ss += v * v;
    }
    __shared__ float bs[256];
    __shared__ float bq[256];
    bs[t] = s; bq[t] = ss;
    __syncthreads();
    if (sub == 0) {
        for (int k = 1; k < nsub; k++) { s += bs[k * C + c]; ss += bq[k * C + c]; }
        atomicAdd(&stats[c], s);
        atomicAdd(&stats[C + c], ss);
    }
}

// nrep: number of stats replicas to sum (fused convs write 8 XCD-local replicas)
template<bool BF16>
__global__ void bn_apply_k(void* __restrict__ Xv, const float* __restrict__ stats,
                           const float* __restrict__ gb, long total, int C, float invn, int nrep)
{
    long tid = (long)blockIdx.x * blockDim.x + threadIdx.x;
    if (tid >= total) return;
    int c = (int)(tid & (C - 1));
    float sm = 0.f, sq = 0.f;
    for (int r = 0; r < nrep; r++) {
        sm += stats[r * 2 * C + c];
        sq += stats[r * 2 * C + C + c];
    }
    float mu  = sm * invn;
    float var = sq * invn - mu * mu;
    float sc  = gb[c] * rsqrtf(var + 1e-5f);
    float x   = BF16 ? b2f(((unsigned short*)Xv)[tid]) : ((float*)Xv)[tid];
    float v   = (x - mu) * sc + gb[C + c];
    v = (v > 0.f) ? v : expm1f(v);
    if (BF16) ((unsigned short*)Xv)[tid] = f2b(v);
    else      ((float*)Xv)[tid] = v;
}

extern "C" void kernel_launch(void* const* d_in, const int* in_sizes, int n_in,
                              void* d_out, int out_size, void* d_ws, size_t ws_size,
                              hipStream_t stream)
{
    const float* feats0  = (const float*)d_in[0];
    const float* feats1  = (const float*)d_in[1];
    const float* feats2  = (const float*)d_in[2];
    const float* w_out0  = (const float*)d_in[3];
    const float* w_out1  = (const float*)d_in[4];
    const float* w_out2  = (const float*)d_in[5];
    const float* wt2     = (const float*)d_in[6];
    const float* wu2     = (const float*)d_in[7];
    const float* wt1     = (const float*)d_in[8];
    const float* wu1     = (const float*)d_in[9];
    const float* bn_out0 = (const float*)d_in[10];
    const float* bn_out1 = (const float*)d_in[11];
    const float* bn_out2 = (const float*)d_in[12];
    const float* bn_up2a = (const float*)d_in[13];
    const float* bn_up2b = (const float*)d_in[14];
    const float* bn_up1a = (const float*)d_in[15];
    const float* bn_up1b = (const float*)d_in[16];
    const int* m_c2 = (const int*)d_in[19];
    const int* m_g2 = (const int*)d_in[20];
    const int* m_u1 = (const int*)d_in[21];
    const int* m_g1 = (const int*)d_in[22];
    const int* m_u0 = (const int*)d_in[23];
    const int* lat1 = (const int*)d_in[24];
    const int* up1  = (const int*)d_in[25];
    const int* lat0 = (const int*)d_in[26];
    const int* up0  = (const int*)d_in[27];

    const int N0  = in_sizes[0] / 64;
    const int N1  = in_sizes[1] / 128;
    const int N2  = in_sizes[2] / 256;
    const int U1  = in_sizes[17] / 128;
    const int U0  = in_sizes[18] / 64;
    const int G2n = in_sizes[25];        // 8*N2
    const int G1n = in_sizes[27];        // 8*U1
    const int Mc2 = in_sizes[19] / 52;
    const int Mg2 = in_sizes[20] / 52;
    const int Mu1 = in_sizes[21] / 52;
    const int Mg1 = in_sizes[22] / 52;
    const int Mu0 = in_sizes[23] / 52;

    float* out0 = (float*)d_out;
    float* out1 = out0 + (size_t)U0 * 128;
    float* out2 = out1 + (size_t)U1 * 128;

    // ---- workspace (256B-aligned bump allocator) ----
    char* wp = (char*)d_ws;
    auto alloc = [&](size_t bytes) -> char* {
        char* r = wp; wp += (bytes + 255) & ~(size_t)255; return r;
    };
    float*          x0   = (float*)alloc((size_t)U0 * 64 * 4);   // tab_g1 aliases (built before x0 written)
    unsigned short* t1   = (unsigned short*)alloc((size_t)(G1n + 1) * 64 * 2);  // tab_u0 aliases t1|t1c (both dead)
    unsigned short* t1c  = (unsigned short*)alloc((size_t)(G1n + 1) * 64 * 2);
    unsigned short* t2   = (unsigned short*)alloc((size_t)(G2n + 1) * 128 * 2);
    unsigned short* t2c  = (unsigned short*)alloc((size_t)(G2n + 1) * 128 * 2);
    float*          x1   = (float*)alloc((size_t)U1 * 128 * 4);
    unsigned short* x1b  = (unsigned short*)alloc((size_t)(U1 + 1) * 128 * 2);
    unsigned short* x0b  = (unsigned short*)alloc((size_t)(U0 + 1) * 64 * 2);
    unsigned short* f2bb = (unsigned short*)alloc((size_t)(N2 + 1) * 256 * 2);
    unsigned short* pc2  = (unsigned short*)alloc((size_t)27 * 256 * 128 * 2);
    unsigned short* pt2  = (unsigned short*)alloc((size_t)8  * 256 * 128 * 2);
    unsigned short* pg2  = (unsigned short*)alloc((size_t)27 * 128 * 128 * 2);
    unsigned short* pu1  = (unsigned short*)alloc((size_t)27 * 128 * 128 * 2);
    unsigned short* pt1  = (unsigned short*)alloc((size_t)8  * 128 * 64  * 2);
    unsigned short* pg1  = (unsigned short*)alloc((size_t)27 * 64  * 64  * 2);
    unsigned short* pu0  = (unsigned short*)alloc((size_t)27 * 64  * 128 * 2);
    int maxSmall = (U1 > G2n) ? U1 : G2n;
    int*   smallTab = (int*)alloc((size_t)maxSmall * 27 * 4);
    float* stats    = (float*)alloc(8 * 2 * 128 * 4);   // 8 replicas x (sum,sumsq) x up to 128 ch
    int* tab_g1 = (int*)x0;   // G1n*27*4  <= U0*64*4 since U0 >= G1n
    int* tab_u0 = (int*)t1;   // U0*27*4   <= t1+t1c region (both dead by then)

    // ---- zero rows for branch-free gathers (index n of every conv input) ----
    hipMemsetAsync(f2bb + (size_t)N2  * 256, 0, 256 * 2, stream);
    hipMemsetAsync(t2   + (size_t)G2n * 128, 0, 128 * 2, stream);
    hipMemsetAsync(x1b  + (size_t)U1  * 128, 0, 128 * 2, stream);
    hipMemsetAsync(t1   + (size_t)G1n * 64,  0, 64  * 2, stream);
    hipMemsetAsync(x0b  + (size_t)U0  * 64,  0, 64  * 2, stream);

    auto packW = [&](const float* W, unsigned short* P, int taps, int l2co, int l2kc) {
        int total = taps * ((1 << l2kc) * 32) * (1 << l2co);
        pack_w<<<dim3((total + 255) / 256), dim3(256), 0, stream>>>(W, P, total, l2co, l2kc);
    };
    auto cast = [&](const float* X, unsigned short* Y, long nElem) {
        cast_bf16<<<dim3((int)((nElem + 255) / 256)), dim3(256), 0, stream>>>(X, Y, (int)nElem);
    };
    auto buildTab = [&](int* tab, const int* map, int M, int n) {
        table_init<<<dim3((n * 27 + 255) / 256), dim3(256), 0, stream>>>(tab, n);
        table_fill<<<dim3((26 * M + 255) / 256), dim3(256), 0, stream>>>(tab, map, M, n);
    };
    auto conv = [&](const unsigned short* Xb, const unsigned short* P, const int* tab,
                    void* Out, int n, int Cin, int Cout, bool outbf16, float* st) {
        int KC = Cin / 32;
        if (n >= 12000) {
            if (Cout == 128 && KC == 2) {
                int nblk = (n + 63) / 64;
                dim3 g(nblk), b(256);
                if (outbf16) conv_mfma_st<2, 2, 4, true ><<<g, b, 0, stream>>>(Xb, P, tab, Out, st, n, nblk);
                else         conv_mfma_st<2, 2, 4, false><<<g, b, 0, stream>>>(Xb, P, tab, Out, st, n, nblk);
                return;
            }
            if (Cout == 64 && KC == 2) {
                int nblk = (n + 63) / 64;
                dim3 g(nblk), b(256);
                if (outbf16) conv_mfma_st<1, 2, 4, true ><<<g, b, 0, stream>>>(Xb, P, tab, Out, st, n, nblk);
                else         conv_mfma_st<1, 2, 4, false><<<g, b, 0, stream>>>(Xb, P, tab, Out, st, n, nblk);
                return;
            }
            if (Cout == 128 && KC == 4) {
                int nblk = (n + 31) / 32;
                dim3 g(nblk), b(256);
                if (outbf16) conv_mfma_st<2, 4, 2, true ><<<g, b, 0, stream>>>(Xb, P, tab, Out, st, n, nblk);
                else         conv_mfma_st<2, 4, 2, false><<<g, b, 0, stream>>>(Xb, P, tab, Out, st, n, nblk);
                return;
            }
        }
        int RB = (n >= 12000) ? 2 : 1;
        int nblk = (n + RB * 16 - 1) / (RB * 16);
        dim3 g(nblk), b(256);
        #define CONV_CASE(T_, RB_)                                                                        \
            if (Cout == 64 * T_ && RB == RB_) {                                                           \
                if (outbf16) conv_mfma<T_, RB_, true ><<<g, b, 0, stream>>>(Xb, P, tab, Out, n, Cin, KC, nblk); \
                else         conv_mfma<T_, RB_, false><<<g, b, 0, stream>>>(Xb, P, tab, Out, n, Cin, KC, nblk); \
                return;                                                                                   \
            }
        CONV_CASE(2, 2) CONV_CASE(2, 1)
        CONV_CASE(1, 2) CONV_CASE(1, 1)
        #undef CONV_CASE
    };
    auto bnapply = [&](void* X, const float* gb, int n, int C, bool bf16, int nrep) {
        long total = (long)n * C;
        if (bf16) bn_apply_k<true ><<<dim3((int)((total + 255) / 256)), dim3(256), 0, stream>>>(X, stats, gb, total, C, 1.0f / n, nrep);
        else      bn_apply_k<false><<<dim3((int)((total + 255) / 256)), dim3(256), 0, stream>>>(X, stats, gb, total, C, 1.0f / n, nrep);
    };
    auto bnelu = [&](void* X, const float* gb, int n, int C, bool bf16) {
        hipMemsetAsync(stats, 0, 2 * C * sizeof(float), stream);
        const int rpb = 512;
        if (bf16) bn_stats_k<true ><<<dim3((n + rpb - 1) / rpb), dim3(256), 0, stream>>>(X, stats, n, C, rpb);
        else      bn_stats_k<false><<<dim3((n + rpb - 1) / rpb), dim3(256), 0, stream>>>(X, stats, n, C, rpb);
        bnapply(X, gb, n, C, bf16, 1);
    };

    // ---- weight packs + input cast ----
    cast(feats2, f2bb, (long)N2 * 256);
    packW(w_out2, pc2, 27, 7, 3);
    packW(wt2,    pt2,  8, 7, 3);
    packW(wu2,    pg2, 27, 7, 2);
    packW(w_out1, pu1, 27, 7, 2);
    packW(wt1,    pt1,  8, 6, 2);
    packW(wu1,    pg1, 27, 6, 1);
    packW(w_out0, pu0, 27, 7, 1);

    // ---- level 2 ----
    buildTab(smallTab, m_c2, Mc2, N2);
    conv(f2bb, pc2, smallTab, out2, N2, 256, 128, false, nullptr);
    bnelu(out2, bn_out2, N2, 128, false);
    tconv_mfma<8, 2><<<dim3((N2 + 15) / 16), dim3(256), 0, stream>>>(f2bb, pt2, t2, N2);
    bnelu(t2, bn_up2a, G2n, 128, true);
    buildTab(smallTab, m_g2, Mg2, G2n);
    conv(t2, pg2, smallTab, t2c, G2n, 128, 128, true, nullptr);
    bnelu(t2c, bn_up2b, G2n, 128, true);

    // ---- level 1 ----
    hipMemsetAsync(x1, 0, (size_t)U1 * 128 * sizeof(float), stream);
    {
        long tot = (long)N1 * 128;
        scatter_add_f32<<<dim3((int)((tot + 255) / 256)), dim3(256), 0, stream>>>(x1, feats1, lat1, tot, 128);
        tot = (long)G2n * 128;
        scatter_add_b16<<<dim3((int)((tot + 255) / 256)), dim3(256), 0, stream>>>(x1, t2c, up1, tot, 128);
    }
    cast(x1, x1b, (long)U1 * 128);
    buildTab(smallTab, m_u1, Mu1, U1);
    hipMemsetAsync(stats, 0, 8 * 2 * 128 * sizeof(float), stream);
    conv(x1b, pu1, smallTab, out1, U1, 128, 128, false, stats);
    bnapply(out1, bn_out1, U1, 128, false, 8);
    tconv_mfma<4, 1><<<dim3((U1 + 15) / 16), dim3(256), 0, stream>>>(x1b, pt1, t1, U1);
    bnelu(t1, bn_up1a, G1n, 64, true);
    buildTab(tab_g1, m_g1, Mg1, G1n);
    hipMemsetAsync(stats, 0, 8 * 2 * 64 * sizeof(float), stream);
    conv(t1, pg1, tab_g1, t1c, G1n, 64, 64, true, stats);
    bnapply(t1c, bn_up1b, G1n, 64, true, 8);

    // ---- level 0 ----
    hipMemsetAsync(x0, 0, (size_t)U0 * 64 * sizeof(float), stream);
    {
        long tot = (long)N0 * 64;
        scatter_add_f32<<<dim3((int)((tot + 255) / 256)), dim3(256), 0, stream>>>(x0, feats0, lat0, tot, 64);
        tot = (long)G1n * 64;
        scatter_add_b16<<<dim3((int)((tot + 255) / 256)), dim3(256), 0, stream>>>(x0, t1c, up0, tot, 64);
    }
    buildTab(tab_u0, m_u0, Mu0, U0);
    cast(x0, x0b, (long)U0 * 64);
    hipMemsetAsync(stats, 0, 8 * 2 * 128 * sizeof(float), stream);
    conv(x0b, pu0, tab_u0, out0, U0, 64, 128, false, stats);
    bnapply(out0, bn_out0, U0, 128, false, 8);
}

// Round 12
// 1046.446 us; speedup vs baseline: 1.1971x; 1.0346x over previous
//
#include <hip/hip_runtime.h>

typedef __bf16 bf16x8 __attribute__((ext_vector_type(8)));
typedef float  f32x4  __attribute__((ext_vector_type(4)));

__device__ __forceinline__ float b2f(unsigned short u) {
    union { unsigned int i; float f; } v; v.i = ((unsigned int)u) << 16; return v.f;
}
__device__ __forceinline__ unsigned short f2b(float f) {
    union { float f; unsigned int i; } v; v.f = f;
    unsigned int u = v.i;
    return (unsigned short)((u + 0x7fffu + ((u >> 16) & 1u)) >> 16);
}

// ---------------- tap table build ----------------
// invalid taps point at the zero row (index n) -> branch-free gathers in conv.
__global__ void table_init(int* __restrict__ tab, int n)
{
    int idx = blockIdx.x * blockDim.x + threadIdx.x;
    if (idx >= n * 27) return;
    tab[idx] = ((idx % 27) == 13) ? (idx / 27) : n;
}

__global__ void table_fill(int* __restrict__ tab, const int* __restrict__ map, int M, int n)
{
    int tid = blockIdx.x * blockDim.x + threadIdx.x;
    if (tid >= 26 * M) return;
    int j = tid / M, q = tid - j * M;
    int om = map[(26 + j) * M + q];
    if (om < n) {
        int k = (j < 13) ? j : j + 1;
        tab[om * 27 + k] = map[j * M + q];
    }
}

// ---------------- weight pack: W[j][k][cout] f32 -> B-fragment order bf16 ----------------
__global__ void pack_w(const float* __restrict__ W, unsigned short* __restrict__ P,
                       int total, int log2Cout, int log2KC)
{
    int tid = blockIdx.x * blockDim.x + threadIdx.x;
    if (tid >= total) return;
    int jj   = tid & 7;
    int cout = (tid >> 3) & ((1 << log2Cout) - 1);
    int rest = tid >> (3 + log2Cout);
    int quad = rest & 3;
    int kj   = rest >> 2;
    int kc   = kj & ((1 << log2KC) - 1);
    int j    = kj >> log2KC;
    int Cin  = (1 << log2KC) * 32;
    int Cout = 1 << log2Cout;
    P[tid] = f2b(W[((size_t)j * Cin + kc * 32 + quad * 8 + jj) * Cout + cout]);
}

__global__ void cast_bf16(const float* __restrict__ X, unsigned short* __restrict__ Y, int nElem)
{
    int tid = blockIdx.x * blockDim.x + threadIdx.x;
    if (tid < nElem) Y[tid] = f2b(X[tid]);
}

// ---------------- staged MFMA sparse conv (big levels) ----------------
// Round-8 structure (best measured: u0=119us, total 993us): 256 threads = 4
// waves; wave owns T*16 couts; block owns RT*16 rows. Block cooperatively
// stages the gathered A rows into LDS once per tap (coalesced 16B chunks),
// single-depth double buffer: loads for tap j+1 issue before MFMA(j), ds_write
// after; one barrier per tap. Reg staging (NOT global_load_lds: DMA gather
// measured slower, r11; NOT depth-2: spills, r9/r10).
// Fused BN stats epilogue with 8 XCD-LOCAL replicas: under the swizzle
// bid&7 == XCD, so each replica's cache lines stay on one die -> no cross-XCD
// atomic ping-pong (round-8's contended single-buffer cost ~26us on u0).
template<int T, int KC, int RT, bool OUTBF16>
__global__ __launch_bounds__(256) void conv_mfma_st(
    const unsigned short* __restrict__ Xb, const unsigned short* __restrict__ P,
    const int* __restrict__ tab, void* __restrict__ OutV, float* __restrict__ St,
    int n, int nblk)
{
    constexpr int Cin = KC * 32, Cout = 64 * T;
    constexpr int ROWS = RT * 16;
    constexpr int STRIDE = KC * 32 + 8;   // shorts; odd multiple of 16B
    constexpr int CHUNKS = KC * 4;        // 16B chunks per row
    constexpr int RPR = 256 / CHUNKS;     // rows staged per round
    constexpr int NRD = ROWS / RPR;       // staging rounds
    __shared__ int tps[ROWS * 27];
    __shared__ unsigned short abuf[2][ROWS * STRIDE];

    const int t = threadIdx.x, lane = t & 63, wv = t >> 6;
    const int m = lane & 15, quad = lane >> 4;

    // bijective chunked XCD swizzle (keeps gather footprint in one XCD's L2)
    const int q = nblk >> 3, rr = nblk & 7;
    const int xcd = blockIdx.x & 7, pos = blockIdx.x >> 3;
    const int bswz = (xcd < rr) ? (xcd * (q + 1) + pos) : (rr * (q + 1) + (xcd - rr) * q + pos);
    const int r0 = bswz * ROWS;
    int rows = n - r0; if (rows > ROWS) rows = ROWS;

    for (int e = t; e < ROWS * 27; e += 256)
        tps[e] = (e < rows * 27) ? tab[(size_t)r0 * 27 + e] : n;
    __syncthreads();

    const int sr = t / CHUNKS;   // staging row-slot within a round
    const int sc = t % CHUNKS;   // staging 16B chunk

    f32x4 acc[RT][T];
    #pragma unroll
    for (int rt = 0; rt < RT; rt++)
        #pragma unroll
        for (int c = 0; c < T; c++) acc[rt][c] = f32x4{0.f, 0.f, 0.f, 0.f};

    uint4 sreg[NRD];

    // prologue: stage tap 0 into buf 0
    #pragma unroll
    for (int rd = 0; rd < NRD; rd++) {
        int r = rd * RPR + sr;
        int in = tps[r * 27];
        sreg[rd] = *reinterpret_cast<const uint4*>(Xb + (size_t)in * Cin + sc * 8);
    }
    #pragma unroll
    for (int rd = 0; rd < NRD; rd++) {
        int r = rd * RPR + sr;
        *reinterpret_cast<uint4*>(&abuf[0][r * STRIDE + sc * 8]) = sreg[rd];
    }
    __syncthreads();

    for (int j = 0; j < 27; j++) {
        const int cur = j & 1;
        // issue global loads for j+1 early (latency hides under MFMA below)
        if (j + 1 < 27) {
            #pragma unroll
            for (int rd = 0; rd < NRD; rd++) {
                int r = rd * RPR + sr;
                int in = tps[r * 27 + j + 1];
                sreg[rd] = *reinterpret_cast<const uint4*>(Xb + (size_t)in * Cin + sc * 8);
            }
        }
        #pragma unroll
        for (int kc = 0; kc < KC; kc++) {
            bf16x8 a[RT];
            #pragma unroll
            for (int rt = 0; rt < RT; rt++)
                a[rt] = *reinterpret_cast<const bf16x8*>(&abuf[cur][(rt * 16 + m) * STRIDE + kc * 32 + quad * 8]);
            const unsigned short* bp = P + ((size_t)((j * KC + kc) * 4 + quad) * Cout + wv * (T * 16)) * 8;
            #pragma unroll
            for (int c = 0; c < T; c++) {
                bf16x8 b = *reinterpret_cast<const bf16x8*>(bp + (c * 16 + m) * 8);
                #pragma unroll
                for (int rt = 0; rt < RT; rt++)
                    acc[rt][c] = __builtin_amdgcn_mfma_f32_16x16x32_bf16(a[rt], b, acc[rt][c], 0, 0, 0);
            }
        }
        // write j+1 into the other buffer (current readers use buf cur)
        if (j + 1 < 27) {
            #pragma unroll
            for (int rd = 0; rd < NRD; rd++) {
                int r = rd * RPR + sr;
                *reinterpret_cast<uint4*>(&abuf[cur ^ 1][r * STRIDE + sc * 8]) = sreg[rd];
            }
        }
        __syncthreads();
    }

    #pragma unroll
    for (int c = 0; c < T; c++) {
        const int cout = (wv * T + c) * 16 + m;
        float s = 0.f, ss = 0.f;
        #pragma unroll
        for (int rt = 0; rt < RT; rt++) {
            #pragma unroll
            for (int reg = 0; reg < 4; reg++) {
                int r = rt * 16 + quad * 4 + reg;
                if (r < rows) {
                    float v = acc[rt][c][reg];
                    size_t off = (size_t)(r0 + r) * Cout + cout;
                    if (OUTBF16) {
                        unsigned short h = f2b(v);
                        ((unsigned short*)OutV)[off] = h;
                        v = b2f(h);
                    } else {
                        ((float*)OutV)[off] = v;
                    }
                    s += v; ss += v * v;
                }
            }
        }
        if (St) {
            s  += __shfl_xor(s, 16);  ss += __shfl_xor(ss, 16);
            s  += __shfl_xor(s, 32);  ss += __shfl_xor(ss, 32);
            if (quad == 0) {
                float* Sr = St + (size_t)(blockIdx.x & 7) * 2 * Cout;  // XCD-local replica
                atomicAdd(&Sr[cout], s);
                atomicAdd(&Sr[Cout + cout], ss);
            }
        }
    }
}

// ---------------- MFMA output-centric sparse conv (small levels) ----------------
template<int T, int RB, bool OUTBF16>
__global__ __launch_bounds__(256) void conv_mfma(
    const unsigned short* __restrict__ Xb, const unsigned short* __restrict__ P,
    const int* __restrict__ tab, void* __restrict__ OutV, int n, int Cin, int KC, int nblk)
{
    const int Cout = 64 * T;
    const int ROWS = RB * 16;
    __shared__ int tps[RB * 16 * 27];
    __shared__ int vld[27];
    const int t = threadIdx.x, lane = t & 63, wv = t >> 6;
    const int m = lane & 15, quad = lane >> 4;

    const int q = nblk >> 3, rr = nblk & 7;
    const int xcd = blockIdx.x & 7, pos = blockIdx.x >> 3;
    const int bswz = (xcd < rr) ? (xcd * (q + 1) + pos) : (rr * (q + 1) + (xcd - rr) * q + pos);
    const int r0 = bswz * ROWS;
    int rows = n - r0; if (rows > ROWS) rows = ROWS;

    for (int e = t; e < ROWS * 27; e += 256)
        tps[e] = (e < rows * 27) ? tab[(size_t)r0 * 27 + e] : n;
    __syncthreads();
    if constexpr (RB == 1) {
        if (t < 27) {
            int v = 0;
            for (int r = 0; r < 16; r++) v |= (tps[r * 27 + t] < n) ? 1 : 0;
            vld[t] = v;
        }
        __syncthreads();
    }

    f32x4 acc[RB][T];
    #pragma unroll
    for (int rt = 0; rt < RB; rt++)
        #pragma unroll
        for (int c = 0; c < T; c++) acc[rt][c] = f32x4{0.f, 0.f, 0.f, 0.f};

    const unsigned short* Xq = Xb + quad * 8;
    const unsigned short* Pq = P + ((size_t)quad * Cout + wv * (T * 16)) * 8;

    for (int j = 0; j < 27; j++) {
        if constexpr (RB == 1) {
            if (!vld[j]) continue;
        }
        int in[RB];
        #pragma unroll
        for (int rt = 0; rt < RB; rt++) in[rt] = tps[(rt * 16 + m) * 27 + j];
        for (int kc = 0; kc < KC; kc++) {
            bf16x8 a[RB];
            #pragma unroll
            for (int rt = 0; rt < RB; rt++)
                a[rt] = *reinterpret_cast<const bf16x8*>(Xq + (size_t)in[rt] * Cin + kc * 32);
            const unsigned short* bp = Pq + (size_t)((j * KC + kc) * 4) * Cout * 8;
            #pragma unroll
            for (int c = 0; c < T; c++) {
                bf16x8 b = *reinterpret_cast<const bf16x8*>(bp + (c * 16 + m) * 8);
                #pragma unroll
                for (int rt = 0; rt < RB; rt++)
                    acc[rt][c] = __builtin_amdgcn_mfma_f32_16x16x32_bf16(a[rt], b, acc[rt][c], 0, 0, 0);
            }
        }
    }

    #pragma unroll
    for (int c = 0; c < T; c++) {
        int cout = (wv * T + c) * 16 + m;
        #pragma unroll
        for (int rt = 0; rt < RB; rt++) {
            #pragma unroll
            for (int reg = 0; reg < 4; reg++) {
                int r = rt * 16 + quad * 4 + reg;
                if (r < rows) {
                    size_t off = (size_t)(r0 + r) * Cout + cout;
                    if (OUTBF16) ((unsigned short*)OutV)[off] = f2b(acc[rt][c][reg]);
                    else         ((float*)OutV)[off] = acc[rt][c][reg];
                }
            }
        }
    }
}

// ---------------- MFMA transpose conv: 8 children per row, A held in regs ----------------
template<int KC, int T>
__global__ __launch_bounds__(256) void tconv_mfma(
    const unsigned short* __restrict__ Xb, const unsigned short* __restrict__ P,
    unsigned short* __restrict__ Out, int n)
{
    const int Cin = KC * 32, Cout = 64 * T;
    const int t = threadIdx.x, lane = t & 63, wv = t >> 6;
    const int m = lane & 15, quad = lane >> 4;
    const int r0 = blockIdx.x * 16;
    int rows = n - r0; if (rows > 16) rows = 16;

    bf16x8 a[KC];
    #pragma unroll
    for (int kc = 0; kc < KC; kc++) {
        a[kc] = bf16x8{};
        if (m < rows)
            a[kc] = *reinterpret_cast<const bf16x8*>(Xb + (size_t)(r0 + m) * Cin + kc * 32 + quad * 8);
    }

    for (int o = 0; o < 8; o++) {
        f32x4 acc[T];
        #pragma unroll
        for (int c = 0; c < T; c++) acc[c] = f32x4{0.f, 0.f, 0.f, 0.f};
        #pragma unroll
        for (int kc = 0; kc < KC; kc++) {
            const unsigned short* bp = P + ((size_t)((o * KC + kc) * 4 + quad) * Cout + wv * (T * 16)) * 8;
            #pragma unroll
            for (int c = 0; c < T; c++) {
                bf16x8 b = *reinterpret_cast<const bf16x8*>(bp + (c * 16 + m) * 8);
                acc[c] = __builtin_amdgcn_mfma_f32_16x16x32_bf16(a[kc], b, acc[c], 0, 0, 0);
            }
        }
        #pragma unroll
        for (int c = 0; c < T; c++) {
            int cout = (wv * T + c) * 16 + m;
            #pragma unroll
            for (int reg = 0; reg < 4; reg++) {
                int r = quad * 4 + reg;
                if (r < rows)
                    Out[((size_t)o * n + r0 + r) * Cout + cout] = f2b(acc[c][reg]);
            }
        }
    }
}

// ---------------- misc ----------------
__global__ void scatter_add_f32(float* __restrict__ dst, const float* __restrict__ src,
                                const int* __restrict__ idx, long total, int C)
{
    long tid = (long)blockIdx.x * blockDim.x + threadIdx.x;
    if (tid >= total) return;
    long r = tid / C;
    int  c = (int)(tid - r * C);
    dst[(long)idx[r] * C + c] += src[tid];
}

__global__ void scatter_add_b16(float* __restrict__ dst, const unsigned short* __restrict__ src,
                                const int* __restrict__ idx, long total, int C)
{
    long tid = (long)blockIdx.x * blockDim.x + threadIdx.x;
    if (tid >= total) return;
    long r = tid / C;
    int  c = (int)(tid - r * C);
    dst[(long)idx[r] * C + c] += b2f(src[tid]);
}

template<bool BF16>
__global__ void bn_stats_k(const void* __restrict__ Xv, float* __restrict__ stats,
                           int n, int C, int rowsPerBlock)
{
    const int t = threadIdx.x;
    const int c = t & (C - 1);
    const int sub = t / C;
    const int nsub = 256 / C;
    int r0 = blockIdx.x * rowsPerBlock + sub;
    int r1 = blockIdx.x * rowsPerBlock + rowsPerBlock;
    if (r1 > n) r1 = n;
    float s = 0.f, ss = 0.f;
    for (int r = r0; r < r1; r += nsub) {
        float v = BF16 ? b2f(((const unsigned short*)Xv)[(long)r * C + c])
                       : ((const float*)Xv)[(long)r * C + c];
        s += v; ss += v * v;
    }
    __shared__ float bs[256];
    __shared__ float bq[256];
    bs[t] = s; bq[t] = ss;
    __syncthreads();
    if (sub == 0) {
        for (int k = 1; k < nsub; k++) { s += bs[k * C + c]; ss += bq[k * C + c]; }
        atomicAdd(&stats[c], s);
        atomicAdd(&stats[C + c], ss);
    }
}

// nrep: number of stats replicas to sum (fused convs write 8 XCD-local replicas)
template<bool BF16>
__global__ void bn_apply_k(void* __restrict__ Xv, const float* __restrict__ stats,
                           const float* __restrict__ gb, long total, int C, float invn, int nrep)
{
    long tid = (long)blockIdx.x * blockDim.x + threadIdx.x;
    if (tid >= total) return;
    int c = (int)(tid & (C - 1));
    float sm = 0.f, sq = 0.f;
    for (int r = 0; r < nrep; r++) {
        sm += stats[r * 2 * C + c];
        sq += stats[r * 2 * C + C + c];
    }
    float mu  = sm * invn;
    float var = sq * invn - mu * mu;
    float sc  = gb[c] * rsqrtf(var + 1e-5f);
    float x   = BF16 ? b2f(((unsigned short*)Xv)[tid]) : ((float*)Xv)[tid];
    float v   = (x - mu) * sc + gb[C + c];
    v = (v > 0.f) ? v : expm1f(v);
    if (BF16) ((unsigned short*)Xv)[tid] = f2b(v);
    else      ((float*)Xv)[tid] = v;
}

extern "C" void kernel_launch(void* const* d_in, const int* in_sizes, int n_in,
                              void* d_out, int out_size, void* d_ws, size_t ws_size,
                              hipStream_t stream)
{
    const float* feats0  = (const float*)d_in[0];
    const float* feats1  = (const float*)d_in[1];
    const float* feats2  = (const float*)d_in[2];
    const float* w_out0  = (const float*)d_in[3];
    const float* w_out1  = (const float*)d_in[4];
    const float* w_out2  = (const float*)d_in[5];
    const float* wt2     = (const float*)d_in[6];
    const float* wu2     = (const float*)d_in[7];
    const float* wt1     = (const float*)d_in[8];
    const float* wu1     = (const float*)d_in[9];
    const float* bn_out0 = (const float*)d_in[10];
    const float* bn_out1 = (const float*)d_in[11];
    const float* bn_out2 = (const float*)d_in[12];
    const float* bn_up2a = (const float*)d_in[13];
    const float* bn_up2b = (const float*)d_in[14];
    const float* bn_up1a = (const float*)d_in[15];
    const float* bn_up1b = (const float*)d_in[16];
    const int* m_c2 = (const int*)d_in[19];
    const int* m_g2 = (const int*)d_in[20];
    const int* m_u1 = (const int*)d_in[21];
    const int* m_g1 = (const int*)d_in[22];
    const int* m_u0 = (const int*)d_in[23];
    const int* lat1 = (const int*)d_in[24];
    const int* up1  = (const int*)d_in[25];
    const int* lat0 = (const int*)d_in[26];
    const int* up0  = (const int*)d_in[27];

    const int N0  = in_sizes[0] / 64;
    const int N1  = in_sizes[1] / 128;
    const int N2  = in_sizes[2] / 256;
    const int U1  = in_sizes[17] / 128;
    const int U0  = in_sizes[18] / 64;
    const int G2n = in_sizes[25];        // 8*N2
    const int G1n = in_sizes[27];        // 8*U1
    const int Mc2 = in_sizes[19] / 52;
    const int Mg2 = in_sizes[20] / 52;
    const int Mu1 = in_sizes[21] / 52;
    const int Mg1 = in_sizes[22] / 52;
    const int Mu0 = in_sizes[23] / 52;

    float* out0 = (float*)d_out;
    float* out1 = out0 + (size_t)U0 * 128;
    float* out2 = out1 + (size_t)U1 * 128;

    // ---- workspace (256B-aligned bump allocator) ----
    char* wp = (char*)d_ws;
    auto alloc = [&](size_t bytes) -> char* {
        char* r = wp; wp += (bytes + 255) & ~(size_t)255; return r;
    };
    float*          x0   = (float*)alloc((size_t)U0 * 64 * 4);   // tab_g1 aliases (built before x0 written)
    unsigned short* t1   = (unsigned short*)alloc((size_t)(G1n + 1) * 64 * 2);  // tab_u0 aliases t1|t1c (both dead)
    unsigned short* t1c  = (unsigned short*)alloc((size_t)(G1n + 1) * 64 * 2);
    unsigned short* t2   = (unsigned short*)alloc((size_t)(G2n + 1) * 128 * 2);
    unsigned short* t2c  = (unsigned short*)alloc((size_t)(G2n + 1) * 128 * 2);
    float*          x1   = (float*)alloc((size_t)U1 * 128 * 4);
    unsigned short* x1b  = (unsigned short*)alloc((size_t)(U1 + 1) * 128 * 2);
    unsigned short* x0b  = (unsigned short*)alloc((size_t)(U0 + 1) * 64 * 2);
    unsigned short* f2bb = (unsigned short*)alloc((size_t)(N2 + 1) * 256 * 2);
    unsigned short* pc2  = (unsigned short*)alloc((size_t)27 * 256 * 128 * 2);
    unsigned short* pt2  = (unsigned short*)alloc((size_t)8  * 256 * 128 * 2);
    unsigned short* pg2  = (unsigned short*)alloc((size_t)27 * 128 * 128 * 2);
    unsigned short* pu1  = (unsigned short*)alloc((size_t)27 * 128 * 128 * 2);
    unsigned short* pt1  = (unsigned short*)alloc((size_t)8  * 128 * 64  * 2);
    unsigned short* pg1  = (unsigned short*)alloc((size_t)27 * 64  * 64  * 2);
    unsigned short* pu0  = (unsigned short*)alloc((size_t)27 * 64  * 128 * 2);
    int maxSmall = (U1 > G2n) ? U1 : G2n;
    int*   smallTab = (int*)alloc((size_t)maxSmall * 27 * 4);
    float* stats    = (float*)alloc(8 * 2 * 128 * 4);   // 8 replicas x (sum,sumsq) x up to 128 ch
    int* tab_g1 = (int*)x0;   // G1n*27*4  <= U0*64*4 since U0 >= G1n
    int* tab_u0 = (int*)t1;   // U0*27*4   <= t1+t1c region (both dead by then)

    // ---- zero rows for branch-free gathers (index n of every conv input) ----
    hipMemsetAsync(f2bb + (size_t)N2  * 256, 0, 256 * 2, stream);
    hipMemsetAsync(t2   + (size_t)G2n * 128, 0, 128 * 2, stream);
    hipMemsetAsync(x1b  + (size_t)U1  * 128, 0, 128 * 2, stream);
    hipMemsetAsync(t1   + (size_t)G1n * 64,  0, 64  * 2, stream);
    hipMemsetAsync(x0b  + (size_t)U0  * 64,  0, 64  * 2, stream);

    auto packW = [&](const float* W, unsigned short* P, int taps, int l2co, int l2kc) {
        int total = taps * ((1 << l2kc) * 32) * (1 << l2co);
        pack_w<<<dim3((total + 255) / 256), dim3(256), 0, stream>>>(W, P, total, l2co, l2kc);
    };
    auto cast = [&](const float* X, unsigned short* Y, long nElem) {
        cast_bf16<<<dim3((int)((nElem + 255) / 256)), dim3(256), 0, stream>>>(X, Y, (int)nElem);
    };
    auto buildTab = [&](int* tab, const int* map, int M, int n) {
        table_init<<<dim3((n * 27 + 255) / 256), dim3(256), 0, stream>>>(tab, n);
        table_fill<<<dim3((26 * M + 255) / 256), dim3(256), 0, stream>>>(tab, map, M, n);
    };
    auto conv = [&](const unsigned short* Xb, const unsigned short* P, const int* tab,
                    void* Out, int n, int Cin, int Cout, bool outbf16, float* st) {
        int KC = Cin / 32;
        if (n >= 12000) {
            if (Cout == 128 && KC == 2) {
                int nblk = (n + 63) / 64;
                dim3 g(nblk), b(256);
                if (outbf16) conv_mfma_st<2, 2, 4, true ><<<g, b, 0, stream>>>(Xb, P, tab, Out, st, n, nblk);
                else         conv_mfma_st<2, 2, 4, false><<<g, b, 0, stream>>>(Xb, P, tab, Out, st, n, nblk);
                return;
            }
            if (Cout == 64 && KC == 2) {
                int nblk = (n + 63) / 64;
                dim3 g(nblk), b(256);
                if (outbf16) conv_mfma_st<1, 2, 4, true ><<<g, b, 0, stream>>>(Xb, P, tab, Out, st, n, nblk);
                else         conv_mfma_st<1, 2, 4, false><<<g, b, 0, stream>>>(Xb, P, tab, Out, st, n, nblk);
                return;
            }
            if (Cout == 128 && KC == 4) {
                int nblk = (n + 31) / 32;   // RT=2: 486 blocks (64-row grid was < #CUs)
                dim3 g(nblk), b(256);
                if (outbf16) conv_mfma_st<2, 4, 2, true ><<<g, b, 0, stream>>>(Xb, P, tab, Out, st, n, nblk);
                else         conv_mfma_st<2, 4, 2, false><<<g, b, 0, stream>>>(Xb, P, tab, Out, st, n, nblk);
                return;
            }
        }
        int RB = (n >= 12000) ? 2 : 1;
        int nblk = (n + RB * 16 - 1) / (RB * 16);
        dim3 g(nblk), b(256);
        #define CONV_CASE(T_, RB_)                                                                        \
            if (Cout == 64 * T_ && RB == RB_) {                                                           \
                if (outbf16) conv_mfma<T_, RB_, true ><<<g, b, 0, stream>>>(Xb, P, tab, Out, n, Cin, KC, nblk); \
                else         conv_mfma<T_, RB_, false><<<g, b, 0, stream>>>(Xb, P, tab, Out, n, Cin, KC, nblk); \
                return;                                                                                   \
            }
        CONV_CASE(2, 2) CONV_CASE(2, 1)
        CONV_CASE(1, 2) CONV_CASE(1, 1)
        #undef CONV_CASE
    };
    auto bnapply = [&](void* X, const float* gb, int n, int C, bool bf16, int nrep) {
        long total = (long)n * C;
        if (bf16) bn_apply_k<true ><<<dim3((int)((total + 255) / 256)), dim3(256), 0, stream>>>(X, stats, gb, total, C, 1.0f / n, nrep);
        else      bn_apply_k<false><<<dim3((int)((total + 255) / 256)), dim3(256), 0, stream>>>(X, stats, gb, total, C, 1.0f / n, nrep);
    };
    auto bnelu = [&](void* X, const float* gb, int n, int C, bool bf16) {
        hipMemsetAsync(stats, 0, 2 * C * sizeof(float), stream);
        const int rpb = 512;
        if (bf16) bn_stats_k<true ><<<dim3((n + rpb - 1) / rpb), dim3(256), 0, stream>>>(X, stats, n, C, rpb);
        else      bn_stats_k<false><<<dim3((n + rpb - 1) / rpb), dim3(256), 0, stream>>>(X, stats, n, C, rpb);
        bnapply(X, gb, n, C, bf16, 1);
    };

    // ---- weight packs + input cast ----
    cast(feats2, f2bb, (long)N2 * 256);
    packW(w_out2, pc2, 27, 7, 3);
    packW(wt2,    pt2,  8, 7, 3);
    packW(wu2,    pg2, 27, 7, 2);
    packW(w_out1, pu1, 27, 7, 2);
    packW(wt1,    pt1,  8, 6, 2);
    packW(wu1,    pg1, 27, 6, 1);
    packW(w_out0, pu0, 27, 7, 1);

    // ---- level 2 ----
    buildTab(smallTab, m_c2, Mc2, N2);
    conv(f2bb, pc2, smallTab, out2, N2, 256, 128, false, nullptr);
    bnelu(out2, bn_out2, N2, 128, false);
    tconv_mfma<8, 2><<<dim3((N2 + 15) / 16), dim3(256), 0, stream>>>(f2bb, pt2, t2, N2);
    bnelu(t2, bn_up2a, G2n, 128, true);
    buildTab(smallTab, m_g2, Mg2, G2n);
    conv(t2, pg2, smallTab, t2c, G2n, 128, 128, true, nullptr);
    bnelu(t2c, bn_up2b, G2n, 128, true);

    // ---- level 1 ----
    hipMemsetAsync(x1, 0, (size_t)U1 * 128 * sizeof(float), stream);
    {
        long tot = (long)N1 * 128;
        scatter_add_f32<<<dim3((int)((tot + 255) / 256)), dim3(256), 0, stream>>>(x1, feats1, lat1, tot, 128);
        tot = (long)G2n * 128;
        scatter_add_b16<<<dim3((int)((tot + 255) / 256)), dim3(256), 0, stream>>>(x1, t2c, up1, tot, 128);
    }
    cast(x1, x1b, (long)U1 * 128);
    buildTab(smallTab, m_u1, Mu1, U1);
    hipMemsetAsync(stats, 0, 8 * 2 * 128 * sizeof(float), stream);
    conv(x1b, pu1, smallTab, out1, U1, 128, 128, false, stats);
    bnapply(out1, bn_out1, U1, 128, false, 8);
    tconv_mfma<4, 1><<<dim3((U1 + 15) / 16), dim3(256), 0, stream>>>(x1b, pt1, t1, U1);
    bnelu(t1, bn_up1a, G1n, 64, true);
    buildTab(tab_g1, m_g1, Mg1, G1n);
    hipMemsetAsync(stats, 0, 8 * 2 * 64 * sizeof(float), stream);
    conv(t1, pg1, tab_g1, t1c, G1n, 64, 64, true, stats);
    bnapply(t1c, bn_up1b, G1n, 64, true, 8);

    // ---- level 0 ----
    hipMemsetAsync(x0, 0, (size_t)U0 * 64 * sizeof(float), stream);
    {
        long tot = (long)N0 * 64;
        scatter_add_f32<<<dim3((int)((tot + 255) / 256)), dim3(256), 0, stream>>>(x0, feats0, lat0, tot, 64);
        tot = (long)G1n * 64;
        scatter_add_b16<<<dim3((int)((tot + 255) / 256)), dim3(256), 0, stream>>>(x0, t1c, up0, tot, 64);
    }
    buildTab(tab_u0, m_u0, Mu0, U0);
    cast(x0, x0b, (long)U0 * 64);
    hipMemsetAsync(stats, 0, 8 * 2 * 128 * sizeof(float), stream);
    conv(x0b, pu0, tab_u0, out0, U0, 64, 128, false, stats);
    bnapply(out0, bn_out0, U0, 128, false, 8);
}

// Round 13
// 950.089 us; speedup vs baseline: 1.3185x; 1.1014x over previous
//
#include <hip/hip_runtime.h>

typedef __bf16 bf16x8 __attribute__((ext_vector_type(8)));
typedef float  f32x4  __attribute__((ext_vector_type(4)));
typedef unsigned short u16x8 __attribute__((ext_vector_type(8)));

__device__ __forceinline__ float b2f(unsigned short u) {
    union { unsigned int i; float f; } v; v.i = ((unsigned int)u) << 16; return v.f;
}
__device__ __forceinline__ unsigned short f2b(float f) {
    union { float f; unsigned int i; } v; v.f = f;
    unsigned int u = v.i;
    return (unsigned short)((u + 0x7fffu + ((u >> 16) & 1u)) >> 16);
}

// ---------------- tap table build ----------------
// invalid taps point at the zero row (index n) -> branch-free gathers in conv.
__global__ void table_init(int* __restrict__ tab, int n)
{
    int idx = blockIdx.x * blockDim.x + threadIdx.x;
    if (idx >= n * 27) return;
    tab[idx] = ((idx % 27) == 13) ? (idx / 27) : n;
}

__global__ void table_fill(int* __restrict__ tab, const int* __restrict__ map, int M, int n)
{
    int tid = blockIdx.x * blockDim.x + threadIdx.x;
    if (tid >= 26 * M) return;
    int j = tid / M, q = tid - j * M;
    int om = map[(26 + j) * M + q];
    if (om < n) {
        int k = (j < 13) ? j : j + 1;
        tab[om * 27 + k] = map[j * M + q];
    }
}

// ---------------- weight pack: W[j][k][cout] f32 -> B-fragment order bf16 ----------------
__global__ void pack_w(const float* __restrict__ W, unsigned short* __restrict__ P,
                       int total, int log2Cout, int log2KC)
{
    int tid = blockIdx.x * blockDim.x + threadIdx.x;
    if (tid >= total) return;
    int jj   = tid & 7;
    int cout = (tid >> 3) & ((1 << log2Cout) - 1);
    int rest = tid >> (3 + log2Cout);
    int quad = rest & 3;
    int kj   = rest >> 2;
    int kc   = kj & ((1 << log2KC) - 1);
    int j    = kj >> log2KC;
    int Cin  = (1 << log2KC) * 32;
    int Cout = 1 << log2Cout;
    P[tid] = f2b(W[((size_t)j * Cin + kc * 32 + quad * 8 + jj) * Cout + cout]);
}

__global__ void cast_bf16(const float* __restrict__ X, unsigned short* __restrict__ Y, int nElem)
{
    int tid = blockIdx.x * blockDim.x + threadIdx.x;
    if (tid < nElem) Y[tid] = f2b(X[tid]);
}

// ---------------- staged MFMA sparse conv (big levels) ----------------
// Round-8 structure + XCD-local stats replicas (r12-verified: convs now off the
// top-5). 256 threads = 4 waves; wave owns T*16 couts; block owns RT*16 rows.
// Block cooperatively stages the gathered A rows into LDS once per tap
// (coalesced 16B chunks), single-depth double buffer; one barrier per tap.
// Reg staging (NOT global_load_lds: DMA gather measured slower, r11; NOT
// depth-2: spills, r9/r10).
template<int T, int KC, int RT, bool OUTBF16>
__global__ __launch_bounds__(256) void conv_mfma_st(
    const unsigned short* __restrict__ Xb, const unsigned short* __restrict__ P,
    const int* __restrict__ tab, void* __restrict__ OutV, float* __restrict__ St,
    int n, int nblk)
{
    constexpr int Cin = KC * 32, Cout = 64 * T;
    constexpr int ROWS = RT * 16;
    constexpr int STRIDE = KC * 32 + 8;   // shorts; odd multiple of 16B
    constexpr int CHUNKS = KC * 4;        // 16B chunks per row
    constexpr int RPR = 256 / CHUNKS;     // rows staged per round
    constexpr int NRD = ROWS / RPR;       // staging rounds
    __shared__ int tps[ROWS * 27];
    __shared__ unsigned short abuf[2][ROWS * STRIDE];

    const int t = threadIdx.x, lane = t & 63, wv = t >> 6;
    const int m = lane & 15, quad = lane >> 4;

    // bijective chunked XCD swizzle (keeps gather footprint in one XCD's L2)
    const int q = nblk >> 3, rr = nblk & 7;
    const int xcd = blockIdx.x & 7, pos = blockIdx.x >> 3;
    const int bswz = (xcd < rr) ? (xcd * (q + 1) + pos) : (rr * (q + 1) + (xcd - rr) * q + pos);
    const int r0 = bswz * ROWS;
    int rows = n - r0; if (rows > ROWS) rows = ROWS;

    for (int e = t; e < ROWS * 27; e += 256)
        tps[e] = (e < rows * 27) ? tab[(size_t)r0 * 27 + e] : n;
    __syncthreads();

    const int sr = t / CHUNKS;   // staging row-slot within a round
    const int sc = t % CHUNKS;   // staging 16B chunk

    f32x4 acc[RT][T];
    #pragma unroll
    for (int rt = 0; rt < RT; rt++)
        #pragma unroll
        for (int c = 0; c < T; c++) acc[rt][c] = f32x4{0.f, 0.f, 0.f, 0.f};

    uint4 sreg[NRD];

    // prologue: stage tap 0 into buf 0
    #pragma unroll
    for (int rd = 0; rd < NRD; rd++) {
        int r = rd * RPR + sr;
        int in = tps[r * 27];
        sreg[rd] = *reinterpret_cast<const uint4*>(Xb + (size_t)in * Cin + sc * 8);
    }
    #pragma unroll
    for (int rd = 0; rd < NRD; rd++) {
        int r = rd * RPR + sr;
        *reinterpret_cast<uint4*>(&abuf[0][r * STRIDE + sc * 8]) = sreg[rd];
    }
    __syncthreads();

    for (int j = 0; j < 27; j++) {
        const int cur = j & 1;
        // issue global loads for j+1 early (latency hides under MFMA below)
        if (j + 1 < 27) {
            #pragma unroll
            for (int rd = 0; rd < NRD; rd++) {
                int r = rd * RPR + sr;
                int in = tps[r * 27 + j + 1];
                sreg[rd] = *reinterpret_cast<const uint4*>(Xb + (size_t)in * Cin + sc * 8);
            }
        }
        #pragma unroll
        for (int kc = 0; kc < KC; kc++) {
            bf16x8 a[RT];
            #pragma unroll
            for (int rt = 0; rt < RT; rt++)
                a[rt] = *reinterpret_cast<const bf16x8*>(&abuf[cur][(rt * 16 + m) * STRIDE + kc * 32 + quad * 8]);
            const unsigned short* bp = P + ((size_t)((j * KC + kc) * 4 + quad) * Cout + wv * (T * 16)) * 8;
            #pragma unroll
            for (int c = 0; c < T; c++) {
                bf16x8 b = *reinterpret_cast<const bf16x8*>(bp + (c * 16 + m) * 8);
                #pragma unroll
                for (int rt = 0; rt < RT; rt++)
                    acc[rt][c] = __builtin_amdgcn_mfma_f32_16x16x32_bf16(a[rt], b, acc[rt][c], 0, 0, 0);
            }
        }
        // write j+1 into the other buffer (current readers use buf cur)
        if (j + 1 < 27) {
            #pragma unroll
            for (int rd = 0; rd < NRD; rd++) {
                int r = rd * RPR + sr;
                *reinterpret_cast<uint4*>(&abuf[cur ^ 1][r * STRIDE + sc * 8]) = sreg[rd];
            }
        }
        __syncthreads();
    }

    #pragma unroll
    for (int c = 0; c < T; c++) {
        const int cout = (wv * T + c) * 16 + m;
        float s = 0.f, ss = 0.f;
        #pragma unroll
        for (int rt = 0; rt < RT; rt++) {
            #pragma unroll
            for (int reg = 0; reg < 4; reg++) {
                int r = rt * 16 + quad * 4 + reg;
                if (r < rows) {
                    float v = acc[rt][c][reg];
                    size_t off = (size_t)(r0 + r) * Cout + cout;
                    if (OUTBF16) {
                        unsigned short h = f2b(v);
                        ((unsigned short*)OutV)[off] = h;
                        v = b2f(h);
                    } else {
                        ((float*)OutV)[off] = v;
                    }
                    s += v; ss += v * v;
                }
            }
        }
        if (St) {
            s  += __shfl_xor(s, 16);  ss += __shfl_xor(ss, 16);
            s  += __shfl_xor(s, 32);  ss += __shfl_xor(ss, 32);
            if (quad == 0) {
                float* Sr = St + (size_t)(blockIdx.x & 7) * 2 * Cout;  // XCD-local replica
                atomicAdd(&Sr[cout], s);
                atomicAdd(&Sr[Cout + cout], ss);
            }
        }
    }
}

// ---------------- MFMA output-centric sparse conv (small levels) ----------------
template<int T, int RB, bool OUTBF16>
__global__ __launch_bounds__(256) void conv_mfma(
    const unsigned short* __restrict__ Xb, const unsigned short* __restrict__ P,
    const int* __restrict__ tab, void* __restrict__ OutV, int n, int Cin, int KC, int nblk)
{
    const int Cout = 64 * T;
    const int ROWS = RB * 16;
    __shared__ int tps[RB * 16 * 27];
    __shared__ int vld[27];
    const int t = threadIdx.x, lane = t & 63, wv = t >> 6;
    const int m = lane & 15, quad = lane >> 4;

    const int q = nblk >> 3, rr = nblk & 7;
    const int xcd = blockIdx.x & 7, pos = blockIdx.x >> 3;
    const int bswz = (xcd < rr) ? (xcd * (q + 1) + pos) : (rr * (q + 1) + (xcd - rr) * q + pos);
    const int r0 = bswz * ROWS;
    int rows = n - r0; if (rows > ROWS) rows = ROWS;

    for (int e = t; e < ROWS * 27; e += 256)
        tps[e] = (e < rows * 27) ? tab[(size_t)r0 * 27 + e] : n;
    __syncthreads();
    if constexpr (RB == 1) {
        if (t < 27) {
            int v = 0;
            for (int r = 0; r < 16; r++) v |= (tps[r * 27 + t] < n) ? 1 : 0;
            vld[t] = v;
        }
        __syncthreads();
    }

    f32x4 acc[RB][T];
    #pragma unroll
    for (int rt = 0; rt < RB; rt++)
        #pragma unroll
        for (int c = 0; c < T; c++) acc[rt][c] = f32x4{0.f, 0.f, 0.f, 0.f};

    const unsigned short* Xq = Xb + quad * 8;
    const unsigned short* Pq = P + ((size_t)quad * Cout + wv * (T * 16)) * 8;

    for (int j = 0; j < 27; j++) {
        if constexpr (RB == 1) {
            if (!vld[j]) continue;
        }
        int in[RB];
        #pragma unroll
        for (int rt = 0; rt < RB; rt++) in[rt] = tps[(rt * 16 + m) * 27 + j];
        for (int kc = 0; kc < KC; kc++) {
            bf16x8 a[RB];
            #pragma unroll
            for (int rt = 0; rt < RB; rt++)
                a[rt] = *reinterpret_cast<const bf16x8*>(Xq + (size_t)in[rt] * Cin + kc * 32);
            const unsigned short* bp = Pq + (size_t)((j * KC + kc) * 4) * Cout * 8;
            #pragma unroll
            for (int c = 0; c < T; c++) {
                bf16x8 b = *reinterpret_cast<const bf16x8*>(bp + (c * 16 + m) * 8);
                #pragma unroll
                for (int rt = 0; rt < RB; rt++)
                    acc[rt][c] = __builtin_amdgcn_mfma_f32_16x16x32_bf16(a[rt], b, acc[rt][c], 0, 0, 0);
            }
        }
    }

    #pragma unroll
    for (int c = 0; c < T; c++) {
        int cout = (wv * T + c) * 16 + m;
        #pragma unroll
        for (int rt = 0; rt < RB; rt++) {
            #pragma unroll
            for (int reg = 0; reg < 4; reg++) {
                int r = rt * 16 + quad * 4 + reg;
                if (r < rows) {
                    size_t off = (size_t)(r0 + r) * Cout + cout;
                    if (OUTBF16) ((unsigned short*)OutV)[off] = f2b(acc[rt][c][reg]);
                    else         ((float*)OutV)[off] = acc[rt][c][reg];
                }
            }
        }
    }
}

// ---------------- MFMA transpose conv: 8 children per row, A held in regs ----------------
template<int KC, int T>
__global__ __launch_bounds__(256) void tconv_mfma(
    const unsigned short* __restrict__ Xb, const unsigned short* __restrict__ P,
    unsigned short* __restrict__ Out, int n)
{
    const int Cin = KC * 32, Cout = 64 * T;
    const int t = threadIdx.x, lane = t & 63, wv = t >> 6;
    const int m = lane & 15, quad = lane >> 4;
    const int r0 = blockIdx.x * 16;
    int rows = n - r0; if (rows > 16) rows = 16;

    bf16x8 a[KC];
    #pragma unroll
    for (int kc = 0; kc < KC; kc++) {
        a[kc] = bf16x8{};
        if (m < rows)
            a[kc] = *reinterpret_cast<const bf16x8*>(Xb + (size_t)(r0 + m) * Cin + kc * 32 + quad * 8);
    }

    for (int o = 0; o < 8; o++) {
        f32x4 acc[T];
        #pragma unroll
        for (int c = 0; c < T; c++) acc[c] = f32x4{0.f, 0.f, 0.f, 0.f};
        #pragma unroll
        for (int kc = 0; kc < KC; kc++) {
            const unsigned short* bp = P + ((size_t)((o * KC + kc) * 4 + quad) * Cout + wv * (T * 16)) * 8;
            #pragma unroll
            for (int c = 0; c < T; c++) {
                bf16x8 b = *reinterpret_cast<const bf16x8*>(bp + (c * 16 + m) * 8);
                acc[c] = __builtin_amdgcn_mfma_f32_16x16x32_bf16(a[kc], b, acc[c], 0, 0, 0);
            }
        }
        #pragma unroll
        for (int c = 0; c < T; c++) {
            int cout = (wv * T + c) * 16 + m;
            #pragma unroll
            for (int reg = 0; reg < 4; reg++) {
                int r = quad * 4 + reg;
                if (r < rows)
                    Out[((size_t)o * n + r0 + r) * Cout + cout] = f2b(acc[c][reg]);
            }
        }
    }
}

// ---------------- misc ----------------
__global__ void scatter_add_f32(float* __restrict__ dst, const float* __restrict__ src,
                                const int* __restrict__ idx, long total, int C)
{
    long tid = (long)blockIdx.x * blockDim.x + threadIdx.x;
    if (tid >= total) return;
    long r = tid / C;
    int  c = (int)(tid - r * C);
    dst[(long)idx[r] * C + c] += src[tid];
}

__global__ void scatter_add_b16(float* __restrict__ dst, const unsigned short* __restrict__ src,
                                const int* __restrict__ idx, long total, int C)
{
    long tid = (long)blockIdx.x * blockDim.x + threadIdx.x;
    if (tid >= total) return;
    long r = tid / C;
    int  c = (int)(tid - r * C);
    dst[(long)idx[r] * C + c] += b2f(src[tid]);
}

template<bool BF16>
__global__ void bn_stats_k(const void* __restrict__ Xv, float* __restrict__ stats,
                           int n, int C, int rowsPerBlock)
{
    const int t = threadIdx.x;
    const int c = t & (C - 1);
    const int sub = t / C;
    const int nsub = 256 / C;
    int r0 = blockIdx.x * rowsPerBlock + sub;
    int r1 = blockIdx.x * rowsPerBlock + rowsPerBlock;
    if (r1 > n) r1 = n;
    float s = 0.f, ss = 0.f;
    for (int r = r0; r < r1; r += nsub) {
        float v = BF16 ? b2f(((const unsigned short*)Xv)[(long)r * C + c])
                       : ((const float*)Xv)[(long)r * C + c];
        s += v; ss += v * v;
    }
    __shared__ float bs[256];
    __shared__ float bq[256];
    bs[t] = s; bq[t] = ss;
    __syncthreads();
    if (sub == 0) {
        for (int k = 1; k < nsub; k++) { s += bs[k * C + c]; ss += bq[k * C + c]; }
        atomicAdd(&stats[c], s);
        atomicAdd(&stats[C + c], ss);
    }
}

// fold nrep stats replicas + gamma/beta into per-channel scale/shift:
// y = x*sc[c] + sh[c]  (then ELU).  One tiny launch instead of per-element work.
__global__ void bn_finalize(const float* __restrict__ stats, const float* __restrict__ gb,
                            float* __restrict__ scsh, int C, float invn, int nrep)
{
    int c = threadIdx.x;
    if (c >= C) return;
    float sm = 0.f, sq = 0.f;
    for (int r = 0; r < nrep; r++) {
        sm += stats[r * 2 * C + c];
        sq += stats[r * 2 * C + C + c];
    }
    float mu  = sm * invn;
    float var = sq * invn - mu * mu;
    float sc  = gb[c] * rsqrtf(var + 1e-5f);
    scsh[c]     = sc;
    scsh[C + c] = gb[C + c] - mu * sc;
}

// vectorized BN-apply + ELU.  f32: float4/thread; rows are C-aligned and C is a
// multiple of 4 so a vector never crosses a row -> channels c0..c0+3 contiguous.
__global__ void bn_apply_f32v(float* __restrict__ X, const float* __restrict__ scsh,
                              long total4, int C)
{
    long tid = (long)blockIdx.x * blockDim.x + threadIdx.x;
    if (tid >= total4) return;
    int c0 = (int)((tid * 4) & (C - 1));
    float4 x  = reinterpret_cast<float4*>(X)[tid];
    float4 sc = *reinterpret_cast<const float4*>(&scsh[c0]);
    float4 sh = *reinterpret_cast<const float4*>(&scsh[C + c0]);
    float v0 = x.x * sc.x + sh.x; v0 = (v0 > 0.f) ? v0 : expm1f(v0);
    float v1 = x.y * sc.y + sh.y; v1 = (v1 > 0.f) ? v1 : expm1f(v1);
    float v2 = x.z * sc.z + sh.z; v2 = (v2 > 0.f) ? v2 : expm1f(v2);
    float v3 = x.w * sc.w + sh.w; v3 = (v3 > 0.f) ? v3 : expm1f(v3);
    reinterpret_cast<float4*>(X)[tid] = float4{v0, v1, v2, v3};
}

// bf16: 8 elems (16B)/thread; C multiple of 8 -> channels c0..c0+7 contiguous.
__global__ void bn_apply_b16v(unsigned short* __restrict__ X, const float* __restrict__ scsh,
                              long total8, int C)
{
    long tid = (long)blockIdx.x * blockDim.x + threadIdx.x;
    if (tid >= total8) return;
    int c0 = (int)((tid * 8) & (C - 1));
    u16x8 x = reinterpret_cast<u16x8*>(X)[tid];
    u16x8 y;
    #pragma unroll
    for (int k = 0; k < 8; k++) {
        float v = b2f(x[k]) * scsh[c0 + k] + scsh[C + c0 + k];
        v = (v > 0.f) ? v : expm1f(v);
        y[k] = f2b(v);
    }
    reinterpret_cast<u16x8*>(X)[tid] = y;
}

extern "C" void kernel_launch(void* const* d_in, const int* in_sizes, int n_in,
                              void* d_out, int out_size, void* d_ws, size_t ws_size,
                              hipStream_t stream)
{
    const float* feats0  = (const float*)d_in[0];
    const float* feats1  = (const float*)d_in[1];
    const float* feats2  = (const float*)d_in[2];
    const float* w_out0  = (const float*)d_in[3];
    const float* w_out1  = (const float*)d_in[4];
    const float* w_out2  = (const float*)d_in[5];
    const float* wt2     = (const float*)d_in[6];
    const float* wu2     = (const float*)d_in[7];
    const float* wt1     = (const float*)d_in[8];
    const float* wu1     = (const float*)d_in[9];
    const float* bn_out0 = (const float*)d_in[10];
    const float* bn_out1 = (const float*)d_in[11];
    const float* bn_out2 = (const float*)d_in[12];
    const float* bn_up2a = (const float*)d_in[13];
    const float* bn_up2b = (const float*)d_in[14];
    const float* bn_up1a = (const float*)d_in[15];
    const float* bn_up1b = (const float*)d_in[16];
    const int* m_c2 = (const int*)d_in[19];
    const int* m_g2 = (const int*)d_in[20];
    const int* m_u1 = (const int*)d_in[21];
    const int* m_g1 = (const int*)d_in[22];
    const int* m_u0 = (const int*)d_in[23];
    const int* lat1 = (const int*)d_in[24];
    const int* up1  = (const int*)d_in[25];
    const int* lat0 = (const int*)d_in[26];
    const int* up0  = (const int*)d_in[27];

    const int N0  = in_sizes[0] / 64;
    const int N1  = in_sizes[1] / 128;
    const int N2  = in_sizes[2] / 256;
    const int U1  = in_sizes[17] / 128;
    const int U0  = in_sizes[18] / 64;
    const int G2n = in_sizes[25];        // 8*N2
    const int G1n = in_sizes[27];        // 8*U1
    const int Mc2 = in_sizes[19] / 52;
    const int Mg2 = in_sizes[20] / 52;
    const int Mu1 = in_sizes[21] / 52;
    const int Mg1 = in_sizes[22] / 52;
    const int Mu0 = in_sizes[23] / 52;

    float* out0 = (float*)d_out;
    float* out1 = out0 + (size_t)U0 * 128;
    float* out2 = out1 + (size_t)U1 * 128;

    // ---- workspace (256B-aligned bump allocator) ----
    char* wp = (char*)d_ws;
    auto alloc = [&](size_t bytes) -> char* {
        char* r = wp; wp += (bytes + 255) & ~(size_t)255; return r;
    };
    float*          x0   = (float*)alloc((size_t)U0 * 64 * 4);   // tab_g1 aliases (built before x0 written)
    unsigned short* t1   = (unsigned short*)alloc((size_t)(G1n + 1) * 64 * 2);  // tab_u0 aliases t1|t1c (both dead)
    unsigned short* t1c  = (unsigned short*)alloc((size_t)(G1n + 1) * 64 * 2);
    unsigned short* t2   = (unsigned short*)alloc((size_t)(G2n + 1) * 128 * 2);
    unsigned short* t2c  = (unsigned short*)alloc((size_t)(G2n + 1) * 128 * 2);
    float*          x1   = (float*)alloc((size_t)U1 * 128 * 4);
    unsigned short* x1b  = (unsigned short*)alloc((size_t)(U1 + 1) * 128 * 2);
    unsigned short* x0b  = (unsigned short*)alloc((size_t)(U0 + 1) * 64 * 2);
    unsigned short* f2bb = (unsigned short*)alloc((size_t)(N2 + 1) * 256 * 2);
    unsigned short* pc2  = (unsigned short*)alloc((size_t)27 * 256 * 128 * 2);
    unsigned short* pt2  = (unsigned short*)alloc((size_t)8  * 256 * 128 * 2);
    unsigned short* pg2  = (unsigned short*)alloc((size_t)27 * 128 * 128 * 2);
    unsigned short* pu1  = (unsigned short*)alloc((size_t)27 * 128 * 128 * 2);
    unsigned short* pt1  = (unsigned short*)alloc((size_t)8  * 128 * 64  * 2);
    unsigned short* pg1  = (unsigned short*)alloc((size_t)27 * 64  * 64  * 2);
    unsigned short* pu0  = (unsigned short*)alloc((size_t)27 * 64  * 128 * 2);
    int maxSmall = (U1 > G2n) ? U1 : G2n;
    int*   smallTab = (int*)alloc((size_t)maxSmall * 27 * 4);
    float* stats    = (float*)alloc(8 * 2 * 128 * 4);   // 8 replicas x (sum,sumsq) x up to 128 ch
    float* scsh     = (float*)alloc(2 * 128 * 4);       // folded per-channel scale/shift
    int* tab_g1 = (int*)x0;   // G1n*27*4  <= U0*64*4 since U0 >= G1n
    int* tab_u0 = (int*)t1;   // U0*27*4   <= t1+t1c region (both dead by then)

    // ---- zero rows for branch-free gathers (index n of every conv input) ----
    hipMemsetAsync(f2bb + (size_t)N2  * 256, 0, 256 * 2, stream);
    hipMemsetAsync(t2   + (size_t)G2n * 128, 0, 128 * 2, stream);
    hipMemsetAsync(x1b  + (size_t)U1  * 128, 0, 128 * 2, stream);
    hipMemsetAsync(t1   + (size_t)G1n * 64,  0, 64  * 2, stream);
    hipMemsetAsync(x0b  + (size_t)U0  * 64,  0, 64  * 2, stream);

    auto packW = [&](const float* W, unsigned short* P, int taps, int l2co, int l2kc) {
        int total = taps * ((1 << l2kc) * 32) * (1 << l2co);
        pack_w<<<dim3((total + 255) / 256), dim3(256), 0, stream>>>(W, P, total, l2co, l2kc);
    };
    auto cast = [&](const float* X, unsigned short* Y, long nElem) {
        cast_bf16<<<dim3((int)((nElem + 255) / 256)), dim3(256), 0, stream>>>(X, Y, (int)nElem);
    };
    auto buildTab = [&](int* tab, const int* map, int M, int n) {
        table_init<<<dim3((n * 27 + 255) / 256), dim3(256), 0, stream>>>(tab, n);
        table_fill<<<dim3((26 * M + 255) / 256), dim3(256), 0, stream>>>(tab, map, M, n);
    };
    auto conv = [&](const unsigned short* Xb, const unsigned short* P, const int* tab,
                    void* Out, int n, int Cin, int Cout, bool outbf16, float* st) {
        int KC = Cin / 32;
        if (n >= 12000) {
            if (Cout == 128 && KC == 2) {
                int nblk = (n + 63) / 64;
                dim3 g(nblk), b(256);
                if (outbf16) conv_mfma_st<2, 2, 4, true ><<<g, b, 0, stream>>>(Xb, P, tab, Out, st, n, nblk);
                else         conv_mfma_st<2, 2, 4, false><<<g, b, 0, stream>>>(Xb, P, tab, Out, st, n, nblk);
                return;
            }
            if (Cout == 64 && KC == 2) {
                int nblk = (n + 63) / 64;
                dim3 g(nblk), b(256);
                if (outbf16) conv_mfma_st<1, 2, 4, true ><<<g, b, 0, stream>>>(Xb, P, tab, Out, st, n, nblk);
                else         conv_mfma_st<1, 2, 4, false><<<g, b, 0, stream>>>(Xb, P, tab, Out, st, n, nblk);
                return;
            }
            if (Cout == 128 && KC == 4) {
                int nblk = (n + 31) / 32;   // RT=2: 486 blocks (64-row grid was < #CUs)
                dim3 g(nblk), b(256);
                if (outbf16) conv_mfma_st<2, 4, 2, true ><<<g, b, 0, stream>>>(Xb, P, tab, Out, st, n, nblk);
                else         conv_mfma_st<2, 4, 2, false><<<g, b, 0, stream>>>(Xb, P, tab, Out, st, n, nblk);
                return;
            }
        }
        int RB = (n >= 12000) ? 2 : 1;
        int nblk = (n + RB * 16 - 1) / (RB * 16);
        dim3 g(nblk), b(256);
        #define CONV_CASE(T_, RB_)                                                                        \
            if (Cout == 64 * T_ && RB == RB_) {                                                           \
                if (outbf16) conv_mfma<T_, RB_, true ><<<g, b, 0, stream>>>(Xb, P, tab, Out, n, Cin, KC, nblk); \
                else         conv_mfma<T_, RB_, false><<<g, b, 0, stream>>>(Xb, P, tab, Out, n, Cin, KC, nblk); \
                return;                                                                                   \
            }
        CONV_CASE(2, 2) CONV_CASE(2, 1)
        CONV_CASE(1, 2) CONV_CASE(1, 1)
        #undef CONV_CASE
    };
    auto bnapply = [&](void* X, const float* gb, int n, int C, bool bf16, int nrep) {
        bn_finalize<<<dim3(1), dim3(C), 0, stream>>>(stats, gb, scsh, C, 1.0f / n, nrep);
        if (bf16) {
            long tot8 = (long)n * C / 8;
            bn_apply_b16v<<<dim3((int)((tot8 + 255) / 256)), dim3(256), 0, stream>>>((unsigned short*)X, scsh, tot8, C);
        } else {
            long tot4 = (long)n * C / 4;
            bn_apply_f32v<<<dim3((int)((tot4 + 255) / 256)), dim3(256), 0, stream>>>((float*)X, scsh, tot4, C);
        }
    };
    auto bnelu = [&](void* X, const float* gb, int n, int C, bool bf16) {
        hipMemsetAsync(stats, 0, 2 * C * sizeof(float), stream);
        const int rpb = 512;
        if (bf16) bn_stats_k<true ><<<dim3((n + rpb - 1) / rpb), dim3(256), 0, stream>>>(X, stats, n, C, rpb);
        else      bn_stats_k<false><<<dim3((n + rpb - 1) / rpb), dim3(256), 0, stream>>>(X, stats, n, C, rpb);
        bnapply(X, gb, n, C, bf16, 1);
    };

    // ---- weight packs + input cast ----
    cast(feats2, f2bb, (long)N2 * 256);
    packW(w_out2, pc2, 27, 7, 3);
    packW(wt2,    pt2,  8, 7, 3);
    packW(wu2,    pg2, 27, 7, 2);
    packW(w_out1, pu1, 27, 7, 2);
    packW(wt1,    pt1,  8, 6, 2);
    packW(wu1,    pg1, 27, 6, 1);
    packW(w_out0, pu0, 27, 7, 1);

    // ---- level 2 ----
    buildTab(smallTab, m_c2, Mc2, N2);
    conv(f2bb, pc2, smallTab, out2, N2, 256, 128, false, nullptr);
    bnelu(out2, bn_out2, N2, 128, false);
    tconv_mfma<8, 2><<<dim3((N2 + 15) / 16), dim3(256), 0, stream>>>(f2bb, pt2, t2, N2);
    bnelu(t2, bn_up2a, G2n, 128, true);
    buildTab(smallTab, m_g2, Mg2, G2n);
    conv(t2, pg2, smallTab, t2c, G2n, 128, 128, true, nullptr);
    bnelu(t2c, bn_up2b, G2n, 128, true);

    // ---- level 1 ----
    hipMemsetAsync(x1, 0, (size_t)U1 * 128 * sizeof(float), stream);
    {
        long tot = (long)N1 * 128;
        scatter_add_f32<<<dim3((int)((tot + 255) / 256)), dim3(256), 0, stream>>>(x1, feats1, lat1, tot, 128);
        tot = (long)G2n * 128;
        scatter_add_b16<<<dim3((int)((tot + 255) / 256)), dim3(256), 0, stream>>>(x1, t2c, up1, tot, 128);
    }
    cast(x1, x1b, (long)U1 * 128);
    buildTab(smallTab, m_u1, Mu1, U1);
    hipMemsetAsync(stats, 0, 8 * 2 * 128 * sizeof(float), stream);
    conv(x1b, pu1, smallTab, out1, U1, 128, 128, false, stats);
    bnapply(out1, bn_out1, U1, 128, false, 8);
    tconv_mfma<4, 1><<<dim3((U1 + 15) / 16), dim3(256), 0, stream>>>(x1b, pt1, t1, U1);
    bnelu(t1, bn_up1a, G1n, 64, true);
    buildTab(tab_g1, m_g1, Mg1, G1n);
    hipMemsetAsync(stats, 0, 8 * 2 * 64 * sizeof(float), stream);
    conv(t1, pg1, tab_g1, t1c, G1n, 64, 64, true, stats);
    bnapply(t1c, bn_up1b, G1n, 64, true, 8);

    // ---- level 0 ----
    hipMemsetAsync(x0, 0, (size_t)U0 * 64 * sizeof(float), stream);
    {
        long tot = (long)N0 * 64;
        scatter_add_f32<<<dim3((int)((tot + 255) / 256)), dim3(256), 0, stream>>>(x0, feats0, lat0, tot, 64);
        tot = (long)G1n * 64;
        scatter_add_b16<<<dim3((int)((tot + 255) / 256)), dim3(256), 0, stream>>>(x0, t1c, up0, tot, 64);
    }
    buildTab(tab_u0, m_u0, Mu0, U0);
    cast(x0, x0b, (long)U0 * 64);
    hipMemsetAsync(stats, 0, 8 * 2 * 128 * sizeof(float), stream);
    conv(x0b, pu0, tab_u0, out0, U0, 64, 128, false, stats);
    bnapply(out0, bn_out0, U0, 128, false, 8);
}

// Round 14
// 922.606 us; speedup vs baseline: 1.3578x; 1.0298x over previous
//
#include <hip/hip_runtime.h>

typedef __bf16 bf16x8 __attribute__((ext_vector_type(8)));
typedef float  f32x4  __attribute__((ext_vector_type(4)));
typedef unsigned short u16x8 __attribute__((ext_vector_type(8)));

__device__ __forceinline__ float b2f(unsigned short u) {
    union { unsigned int i; float f; } v; v.i = ((unsigned int)u) << 16; return v.f;
}
__device__ __forceinline__ unsigned short f2b(float f) {
    union { float f; unsigned int i; } v; v.f = f;
    unsigned int u = v.i;
    return (unsigned short)((u + 0x7fffu + ((u >> 16) & 1u)) >> 16);
}

// ---------------- tap table build ----------------
// invalid taps point at the zero row (index n) -> branch-free gathers in conv.
__global__ void table_init(int* __restrict__ tab, int n)
{
    int idx = blockIdx.x * blockDim.x + threadIdx.x;
    if (idx >= n * 27) return;
    tab[idx] = ((idx % 27) == 13) ? (idx / 27) : n;
}

__global__ void table_fill(int* __restrict__ tab, const int* __restrict__ map, int M, int n)
{
    int tid = blockIdx.x * blockDim.x + threadIdx.x;
    if (tid >= 26 * M) return;
    int j = tid / M, q = tid - j * M;
    int om = map[(26 + j) * M + q];
    if (om < n) {
        int k = (j < 13) ? j : j + 1;
        tab[om * 27 + k] = map[j * M + q];
    }
}

// ---------------- weight pack: W[j][k][cout] f32 -> B-fragment order bf16 ----------------
__global__ void pack_w(const float* __restrict__ W, unsigned short* __restrict__ P,
                       int total, int log2Cout, int log2KC)
{
    int tid = blockIdx.x * blockDim.x + threadIdx.x;
    if (tid >= total) return;
    int jj   = tid & 7;
    int cout = (tid >> 3) & ((1 << log2Cout) - 1);
    int rest = tid >> (3 + log2Cout);
    int quad = rest & 3;
    int kj   = rest >> 2;
    int kc   = kj & ((1 << log2KC) - 1);
    int j    = kj >> log2KC;
    int Cin  = (1 << log2KC) * 32;
    int Cout = 1 << log2Cout;
    P[tid] = f2b(W[((size_t)j * Cin + kc * 32 + quad * 8 + jj) * Cout + cout]);
}

__global__ void cast_bf16v(const float* __restrict__ X, unsigned short* __restrict__ Y, long total4)
{
    long tid = (long)blockIdx.x * blockDim.x + threadIdx.x;
    if (tid >= total4) return;
    float4 x = reinterpret_cast<const float4*>(X)[tid];
    ushort4 y{f2b(x.x), f2b(x.y), f2b(x.z), f2b(x.w)};
    reinterpret_cast<ushort4*>(Y)[tid] = y;
}

// ---------------- staged MFMA sparse conv (big levels) ----------------
// Round-8 structure + XCD-local stats replicas (r12/r13-verified). 256 threads
// = 4 waves; wave owns T*16 couts; block owns RT*16 rows. Block cooperatively
// stages the gathered A rows into LDS once per tap (coalesced 16B chunks),
// single-depth double buffer; one barrier per tap. Reg staging (NOT
// global_load_lds: slower, r11; NOT depth-2: spills, r9/r10).
// RT=8 allowed only when T==1 (acc=32 VGPR; T=2xRT8 spilled in r7).
template<int T, int KC, int RT, bool OUTBF16>
__global__ __launch_bounds__(256) void conv_mfma_st(
    const unsigned short* __restrict__ Xb, const unsigned short* __restrict__ P,
    const int* __restrict__ tab, void* __restrict__ OutV, float* __restrict__ St,
    int n, int nblk)
{
    constexpr int Cin = KC * 32, Cout = 64 * T;
    constexpr int ROWS = RT * 16;
    constexpr int STRIDE = KC * 32 + 8;   // shorts; odd multiple of 16B
    constexpr int CHUNKS = KC * 4;        // 16B chunks per row
    constexpr int RPR = 256 / CHUNKS;     // rows staged per round
    constexpr int NRD = ROWS / RPR;       // staging rounds
    __shared__ int tps[ROWS * 27];
    __shared__ unsigned short abuf[2][ROWS * STRIDE];

    const int t = threadIdx.x, lane = t & 63, wv = t >> 6;
    const int m = lane & 15, quad = lane >> 4;

    // bijective chunked XCD swizzle (keeps gather footprint in one XCD's L2)
    const int q = nblk >> 3, rr = nblk & 7;
    const int xcd = blockIdx.x & 7, pos = blockIdx.x >> 3;
    const int bswz = (xcd < rr) ? (xcd * (q + 1) + pos) : (rr * (q + 1) + (xcd - rr) * q + pos);
    const int r0 = bswz * ROWS;
    int rows = n - r0; if (rows > ROWS) rows = ROWS;

    for (int e = t; e < ROWS * 27; e += 256)
        tps[e] = (e < rows * 27) ? tab[(size_t)r0 * 27 + e] : n;
    __syncthreads();

    const int sr = t / CHUNKS;   // staging row-slot within a round
    const int sc = t % CHUNKS;   // staging 16B chunk

    f32x4 acc[RT][T];
    #pragma unroll
    for (int rt = 0; rt < RT; rt++)
        #pragma unroll
        for (int c = 0; c < T; c++) acc[rt][c] = f32x4{0.f, 0.f, 0.f, 0.f};

    uint4 sreg[NRD];

    // prologue: stage tap 0 into buf 0
    #pragma unroll
    for (int rd = 0; rd < NRD; rd++) {
        int r = rd * RPR + sr;
        int in = tps[r * 27];
        sreg[rd] = *reinterpret_cast<const uint4*>(Xb + (size_t)in * Cin + sc * 8);
    }
    #pragma unroll
    for (int rd = 0; rd < NRD; rd++) {
        int r = rd * RPR + sr;
        *reinterpret_cast<uint4*>(&abuf[0][r * STRIDE + sc * 8]) = sreg[rd];
    }
    __syncthreads();

    for (int j = 0; j < 27; j++) {
        const int cur = j & 1;
        // issue global loads for j+1 early (latency hides under MFMA below)
        if (j + 1 < 27) {
            #pragma unroll
            for (int rd = 0; rd < NRD; rd++) {
                int r = rd * RPR + sr;
                int in = tps[r * 27 + j + 1];
                sreg[rd] = *reinterpret_cast<const uint4*>(Xb + (size_t)in * Cin + sc * 8);
            }
        }
        #pragma unroll
        for (int kc = 0; kc < KC; kc++) {
            bf16x8 a[RT];
            #pragma unroll
            for (int rt = 0; rt < RT; rt++)
                a[rt] = *reinterpret_cast<const bf16x8*>(&abuf[cur][(rt * 16 + m) * STRIDE + kc * 32 + quad * 8]);
            const unsigned short* bp = P + ((size_t)((j * KC + kc) * 4 + quad) * Cout + wv * (T * 16)) * 8;
            #pragma unroll
            for (int c = 0; c < T; c++) {
                bf16x8 b = *reinterpret_cast<const bf16x8*>(bp + (c * 16 + m) * 8);
                #pragma unroll
                for (int rt = 0; rt < RT; rt++)
                    acc[rt][c] = __builtin_amdgcn_mfma_f32_16x16x32_bf16(a[rt], b, acc[rt][c], 0, 0, 0);
            }
        }
        // write j+1 into the other buffer (current readers use buf cur)
        if (j + 1 < 27) {
            #pragma unroll
            for (int rd = 0; rd < NRD; rd++) {
                int r = rd * RPR + sr;
                *reinterpret_cast<uint4*>(&abuf[cur ^ 1][r * STRIDE + sc * 8]) = sreg[rd];
            }
        }
        __syncthreads();
    }

    #pragma unroll
    for (int c = 0; c < T; c++) {
        const int cout = (wv * T + c) * 16 + m;
        float s = 0.f, ss = 0.f;
        #pragma unroll
        for (int rt = 0; rt < RT; rt++) {
            #pragma unroll
            for (int reg = 0; reg < 4; reg++) {
                int r = rt * 16 + quad * 4 + reg;
                if (r < rows) {
                    float v = acc[rt][c][reg];
                    size_t off = (size_t)(r0 + r) * Cout + cout;
                    if (OUTBF16) {
                        unsigned short h = f2b(v);
                        ((unsigned short*)OutV)[off] = h;
                        v = b2f(h);
                    } else {
                        ((float*)OutV)[off] = v;
                    }
                    s += v; ss += v * v;
                }
            }
        }
        if (St) {
            s  += __shfl_xor(s, 16);  ss += __shfl_xor(ss, 16);
            s  += __shfl_xor(s, 32);  ss += __shfl_xor(ss, 32);
            if (quad == 0) {
                float* Sr = St + (size_t)(blockIdx.x & 7) * 2 * Cout;  // XCD-local replica
                atomicAdd(&Sr[cout], s);
                atomicAdd(&Sr[Cout + cout], ss);
            }
        }
    }
}

// ---------------- MFMA output-centric sparse conv (small levels) ----------------
template<int T, int RB, bool OUTBF16>
__global__ __launch_bounds__(256) void conv_mfma(
    const unsigned short* __restrict__ Xb, const unsigned short* __restrict__ P,
    const int* __restrict__ tab, void* __restrict__ OutV, int n, int Cin, int KC, int nblk)
{
    const int Cout = 64 * T;
    const int ROWS = RB * 16;
    __shared__ int tps[RB * 16 * 27];
    __shared__ int vld[27];
    const int t = threadIdx.x, lane = t & 63, wv = t >> 6;
    const int m = lane & 15, quad = lane >> 4;

    const int q = nblk >> 3, rr = nblk & 7;
    const int xcd = blockIdx.x & 7, pos = blockIdx.x >> 3;
    const int bswz = (xcd < rr) ? (xcd * (q + 1) + pos) : (rr * (q + 1) + (xcd - rr) * q + pos);
    const int r0 = bswz * ROWS;
    int rows = n - r0; if (rows > ROWS) rows = ROWS;

    for (int e = t; e < ROWS * 27; e += 256)
        tps[e] = (e < rows * 27) ? tab[(size_t)r0 * 27 + e] : n;
    __syncthreads();
    if constexpr (RB == 1) {
        if (t < 27) {
            int v = 0;
            for (int r = 0; r < 16; r++) v |= (tps[r * 27 + t] < n) ? 1 : 0;
            vld[t] = v;
        }
        __syncthreads();
    }

    f32x4 acc[RB][T];
    #pragma unroll
    for (int rt = 0; rt < RB; rt++)
        #pragma unroll
        for (int c = 0; c < T; c++) acc[rt][c] = f32x4{0.f, 0.f, 0.f, 0.f};

    const unsigned short* Xq = Xb + quad * 8;
    const unsigned short* Pq = P + ((size_t)quad * Cout + wv * (T * 16)) * 8;

    for (int j = 0; j < 27; j++) {
        if constexpr (RB == 1) {
            if (!vld[j]) continue;
        }
        int in[RB];
        #pragma unroll
        for (int rt = 0; rt < RB; rt++) in[rt] = tps[(rt * 16 + m) * 27 + j];
        for (int kc = 0; kc < KC; kc++) {
            bf16x8 a[RB];
            #pragma unroll
            for (int rt = 0; rt < RB; rt++)
                a[rt] = *reinterpret_cast<const bf16x8*>(Xq + (size_t)in[rt] * Cin + kc * 32);
            const unsigned short* bp = Pq + (size_t)((j * KC + kc) * 4) * Cout * 8;
            #pragma unroll
            for (int c = 0; c < T; c++) {
                bf16x8 b = *reinterpret_cast<const bf16x8*>(bp + (c * 16 + m) * 8);
                #pragma unroll
                for (int rt = 0; rt < RB; rt++)
                    acc[rt][c] = __builtin_amdgcn_mfma_f32_16x16x32_bf16(a[rt], b, acc[rt][c], 0, 0, 0);
            }
        }
    }

    #pragma unroll
    for (int c = 0; c < T; c++) {
        int cout = (wv * T + c) * 16 + m;
        #pragma unroll
        for (int rt = 0; rt < RB; rt++) {
            #pragma unroll
            for (int reg = 0; reg < 4; reg++) {
                int r = rt * 16 + quad * 4 + reg;
                if (r < rows) {
                    size_t off = (size_t)(r0 + r) * Cout + cout;
                    if (OUTBF16) ((unsigned short*)OutV)[off] = f2b(acc[rt][c][reg]);
                    else         ((float*)OutV)[off] = acc[rt][c][reg];
                }
            }
        }
    }
}

// ---------------- MFMA transpose conv: 8 children per row, A held in regs ----------------
template<int KC, int T>
__global__ __launch_bounds__(256) void tconv_mfma(
    const unsigned short* __restrict__ Xb, const unsigned short* __restrict__ P,
    unsigned short* __restrict__ Out, int n)
{
    const int Cin = KC * 32, Cout = 64 * T;
    const int t = threadIdx.x, lane = t & 63, wv = t >> 6;
    const int m = lane & 15, quad = lane >> 4;
    const int r0 = blockIdx.x * 16;
    int rows = n - r0; if (rows > 16) rows = 16;

    bf16x8 a[KC];
    #pragma unroll
    for (int kc = 0; kc < KC; kc++) {
        a[kc] = bf16x8{};
        if (m < rows)
            a[kc] = *reinterpret_cast<const bf16x8*>(Xb + (size_t)(r0 + m) * Cin + kc * 32 + quad * 8);
    }

    for (int o = 0; o < 8; o++) {
        f32x4 acc[T];
        #pragma unroll
        for (int c = 0; c < T; c++) acc[c] = f32x4{0.f, 0.f, 0.f, 0.f};
        #pragma unroll
        for (int kc = 0; kc < KC; kc++) {
            const unsigned short* bp = P + ((size_t)((o * KC + kc) * 4 + quad) * Cout + wv * (T * 16)) * 8;
            #pragma unroll
            for (int c = 0; c < T; c++) {
                bf16x8 b = *reinterpret_cast<const bf16x8*>(bp + (c * 16 + m) * 8);
                acc[c] = __builtin_amdgcn_mfma_f32_16x16x32_bf16(a[kc], b, acc[c], 0, 0, 0);
            }
        }
        #pragma unroll
        for (int c = 0; c < T; c++) {
            int cout = (wv * T + c) * 16 + m;
            #pragma unroll
            for (int reg = 0; reg < 4; reg++) {
                int r = quad * 4 + reg;
                if (r < rows)
                    Out[((size_t)o * n + r0 + r) * Cout + cout] = f2b(acc[c][reg]);
            }
        }
    }
}

// ---------------- scatter / BN ----------------
// first writer into zeroed buffer, rows unique -> plain store, float4/thread
__global__ void scatter_set_f32v(float* __restrict__ dst, const float* __restrict__ src,
                                 const int* __restrict__ idx, long total4, int C4)
{
    long tid = (long)blockIdx.x * blockDim.x + threadIdx.x;
    if (tid >= total4) return;
    long r = tid / C4;
    int  c4 = (int)(tid - r * C4);
    float4 s = reinterpret_cast<const float4*>(src)[tid];
    reinterpret_cast<float4*>(dst + (long)idx[r] * C4 * 4)[c4] = s;
}

// fused BN(affine)+ELU+scatter-add: reads RAW bf16 conv output, applies
// per-channel scale/shift (pre-folded in scsh) + ELU, adds into f32 dst.
// Eliminates the separate bn_apply pass over t1c/t2c. 8 elems/thread.
__global__ void scatter_bn_add_b16v(float* __restrict__ dst, const unsigned short* __restrict__ src,
                                    const int* __restrict__ idx, const float* __restrict__ scsh,
                                    long total8, int C)
{
    long tid = (long)blockIdx.x * blockDim.x + threadIdx.x;
    if (tid >= total8) return;
    int C8 = C >> 3;
    long r = tid / C8;
    int  c0 = (int)(tid - r * C8) * 8;
    u16x8 x = reinterpret_cast<const u16x8*>(src)[tid];
    float* d = dst + (long)idx[r] * C + c0;
    float4 d0 = *reinterpret_cast<float4*>(d);
    float4 d1 = *reinterpret_cast<float4*>(d + 4);
    float v[8];
    #pragma unroll
    for (int k = 0; k < 8; k++) {
        float w = b2f(x[k]) * scsh[c0 + k] + scsh[C + c0 + k];
        v[k] = (w > 0.f) ? w : expm1f(w);
    }
    d0.x += v[0]; d0.y += v[1]; d0.z += v[2]; d0.w += v[3];
    d1.x += v[4]; d1.y += v[5]; d1.z += v[6]; d1.w += v[7];
    *reinterpret_cast<float4*>(d)     = d0;
    *reinterpret_cast<float4*>(d + 4) = d1;
}

template<bool BF16>
__global__ void bn_stats_k(const void* __restrict__ Xv, float* __restrict__ stats,
                           int n, int C, int rowsPerBlock)
{
    const int t = threadIdx.x;
    const int c = t & (C - 1);
    const int sub = t / C;
    const int nsub = 256 / C;
    int r0 = blockIdx.x * rowsPerBlock + sub;
    int r1 = blockIdx.x * rowsPerBlock + rowsPerBlock;
    if (r1 > n) r1 = n;
    float s = 0.f, ss = 0.f;
    for (int r = r0; r < r1; r += nsub) {
        float v = BF16 ? b2f(((const unsigned short*)Xv)[(long)r * C + c])
                       : ((const float*)Xv)[(long)r * C + c];
        s += v; ss += v * v;
    }
    __shared__ float bs[256];
    __shared__ float bq[256];
    bs[t] = s; bq[t] = ss;
    __syncthreads();
    if (sub == 0) {
        for (int k = 1; k < nsub; k++) { s += bs[k * C + c]; ss += bq[k * C + c]; }
        atomicAdd(&stats[c], s);
        atomicAdd(&stats[C + c], ss);
    }
}

// fold nrep stats replicas + gamma/beta into per-channel scale/shift
__global__ void bn_finalize(const float* __restrict__ stats, const float* __restrict__ gb,
                            float* __restrict__ scsh, int C, float invn, int nrep)
{
    int c = threadIdx.x;
    if (c >= C) return;
    float sm = 0.f, sq = 0.f;
    for (int r = 0; r < nrep; r++) {
        sm += stats[r * 2 * C + c];
        sq += stats[r * 2 * C + C + c];
    }
    float mu  = sm * invn;
    float var = sq * invn - mu * mu;
    float sc  = gb[c] * rsqrtf(var + 1e-5f);
    scsh[c]     = sc;
    scsh[C + c] = gb[C + c] - mu * sc;
}

__global__ void bn_apply_f32v(float* __restrict__ X, const float* __restrict__ scsh,
                              long total4, int C)
{
    long tid = (long)blockIdx.x * blockDim.x + threadIdx.x;
    if (tid >= total4) return;
    int c0 = (int)((tid * 4) & (C - 1));
    float4 x  = reinterpret_cast<float4*>(X)[tid];
    float4 sc = *reinterpret_cast<const float4*>(&scsh[c0]);
    float4 sh = *reinterpret_cast<const float4*>(&scsh[C + c0]);
    float v0 = x.x * sc.x + sh.x; v0 = (v0 > 0.f) ? v0 : expm1f(v0);
    float v1 = x.y * sc.y + sh.y; v1 = (v1 > 0.f) ? v1 : expm1f(v1);
    float v2 = x.z * sc.z + sh.z; v2 = (v2 > 0.f) ? v2 : expm1f(v2);
    float v3 = x.w * sc.w + sh.w; v3 = (v3 > 0.f) ? v3 : expm1f(v3);
    reinterpret_cast<float4*>(X)[tid] = float4{v0, v1, v2, v3};
}

__global__ void bn_apply_b16v(unsigned short* __restrict__ X, const float* __restrict__ scsh,
                              long total8, int C)
{
    long tid = (long)blockIdx.x * blockDim.x + threadIdx.x;
    if (tid >= total8) return;
    int c0 = (int)((tid * 8) & (C - 1));
    u16x8 x = reinterpret_cast<u16x8*>(X)[tid];
    u16x8 y;
    #pragma unroll
    for (int k = 0; k < 8; k++) {
        float v = b2f(x[k]) * scsh[c0 + k] + scsh[C + c0 + k];
        v = (v > 0.f) ? v : expm1f(v);
        y[k] = f2b(v);
    }
    reinterpret_cast<u16x8*>(X)[tid] = y;
}

extern "C" void kernel_launch(void* const* d_in, const int* in_sizes, int n_in,
                              void* d_out, int out_size, void* d_ws, size_t ws_size,
                              hipStream_t stream)
{
    const float* feats0  = (const float*)d_in[0];
    const float* feats1  = (const float*)d_in[1];
    const float* feats2  = (const float*)d_in[2];
    const float* w_out0  = (const float*)d_in[3];
    const float* w_out1  = (const float*)d_in[4];
    const float* w_out2  = (const float*)d_in[5];
    const float* wt2     = (const float*)d_in[6];
    const float* wu2     = (const float*)d_in[7];
    const float* wt1     = (const float*)d_in[8];
    const float* wu1     = (const float*)d_in[9];
    const float* bn_out0 = (const float*)d_in[10];
    const float* bn_out1 = (const float*)d_in[11];
    const float* bn_out2 = (const float*)d_in[12];
    const float* bn_up2a = (const float*)d_in[13];
    const float* bn_up2b = (const float*)d_in[14];
    const float* bn_up1a = (const float*)d_in[15];
    const float* bn_up1b = (const float*)d_in[16];
    const int* m_c2 = (const int*)d_in[19];
    const int* m_g2 = (const int*)d_in[20];
    const int* m_u1 = (const int*)d_in[21];
    const int* m_g1 = (const int*)d_in[22];
    const int* m_u0 = (const int*)d_in[23];
    const int* lat1 = (const int*)d_in[24];
    const int* up1  = (const int*)d_in[25];
    const int* lat0 = (const int*)d_in[26];
    const int* up0  = (const int*)d_in[27];

    const int N0  = in_sizes[0] / 64;
    const int N1  = in_sizes[1] / 128;
    const int N2  = in_sizes[2] / 256;
    const int U1  = in_sizes[17] / 128;
    const int U0  = in_sizes[18] / 64;
    const int G2n = in_sizes[25];        // 8*N2
    const int G1n = in_sizes[27];        // 8*U1
    const int Mc2 = in_sizes[19] / 52;
    const int Mg2 = in_sizes[20] / 52;
    const int Mu1 = in_sizes[21] / 52;
    const int Mg1 = in_sizes[22] / 52;
    const int Mu0 = in_sizes[23] / 52;

    float* out0 = (float*)d_out;
    float* out1 = out0 + (size_t)U0 * 128;
    float* out2 = out1 + (size_t)U1 * 128;

    // ---- workspace (256B-aligned bump allocator) ----
    char* wp = (char*)d_ws;
    auto alloc = [&](size_t bytes) -> char* {
        char* r = wp; wp += (bytes + 255) & ~(size_t)255; return r;
    };
    float*          x0   = (float*)alloc((size_t)U0 * 64 * 4);   // tab_g1 aliases (built before x0 written)
    unsigned short* t1   = (unsigned short*)alloc((size_t)(G1n + 1) * 64 * 2);  // tab_u0 aliases t1|t1c (both dead)
    unsigned short* t1c  = (unsigned short*)alloc((size_t)(G1n + 1) * 64 * 2);
    unsigned short* t2   = (unsigned short*)alloc((size_t)(G2n + 1) * 128 * 2);
    unsigned short* t2c  = (unsigned short*)alloc((size_t)(G2n + 1) * 128 * 2);
    float*          x1   = (float*)alloc((size_t)U1 * 128 * 4);
    unsigned short* x1b  = (unsigned short*)alloc((size_t)(U1 + 1) * 128 * 2);
    unsigned short* x0b  = (unsigned short*)alloc((size_t)(U0 + 1) * 64 * 2);
    unsigned short* f2bb = (unsigned short*)alloc((size_t)(N2 + 1) * 256 * 2);
    unsigned short* pc2  = (unsigned short*)alloc((size_t)27 * 256 * 128 * 2);
    unsigned short* pt2  = (unsigned short*)alloc((size_t)8  * 256 * 128 * 2);
    unsigned short* pg2  = (unsigned short*)alloc((size_t)27 * 128 * 128 * 2);
    unsigned short* pu1  = (unsigned short*)alloc((size_t)27 * 128 * 128 * 2);
    unsigned short* pt1  = (unsigned short*)alloc((size_t)8  * 128 * 64  * 2);
    unsigned short* pg1  = (unsigned short*)alloc((size_t)27 * 64  * 64  * 2);
    unsigned short* pu0  = (unsigned short*)alloc((size_t)27 * 64  * 128 * 2);
    int maxSmall = (U1 > G2n) ? U1 : G2n;
    int*   smallTab = (int*)alloc((size_t)maxSmall * 27 * 4);
    float* stats    = (float*)alloc(8 * 2 * 128 * 4);   // 8 replicas x (sum,sumsq) x up to 128 ch
    float* scsh     = (float*)alloc(2 * 128 * 4);       // folded per-channel scale/shift
    int* tab_g1 = (int*)x0;   // G1n*27*4  <= U0*64*4 since U0 >= G1n
    int* tab_u0 = (int*)t1;   // U0*27*4   <= t1+t1c region (both dead by then)

    // ---- zero rows for branch-free gathers (index n of every conv input) ----
    hipMemsetAsync(f2bb + (size_t)N2  * 256, 0, 256 * 2, stream);
    hipMemsetAsync(t2   + (size_t)G2n * 128, 0, 128 * 2, stream);
    hipMemsetAsync(x1b  + (size_t)U1  * 128, 0, 128 * 2, stream);
    hipMemsetAsync(t1   + (size_t)G1n * 64,  0, 64  * 2, stream);
    hipMemsetAsync(x0b  + (size_t)U0  * 64,  0, 64  * 2, stream);

    auto packW = [&](const float* W, unsigned short* P, int taps, int l2co, int l2kc) {
        int total = taps * ((1 << l2kc) * 32) * (1 << l2co);
        pack_w<<<dim3((total + 255) / 256), dim3(256), 0, stream>>>(W, P, total, l2co, l2kc);
    };
    auto cast = [&](const float* X, unsigned short* Y, long nElem) {
        long tot4 = nElem / 4;
        cast_bf16v<<<dim3((int)((tot4 + 255) / 256)), dim3(256), 0, stream>>>(X, Y, tot4);
    };
    auto buildTab = [&](int* tab, const int* map, int M, int n) {
        table_init<<<dim3((n * 27 + 255) / 256), dim3(256), 0, stream>>>(tab, n);
        table_fill<<<dim3((26 * M + 255) / 256), dim3(256), 0, stream>>>(tab, map, M, n);
    };
    auto conv = [&](const unsigned short* Xb, const unsigned short* P, const int* tab,
                    void* Out, int n, int Cin, int Cout, bool outbf16, float* st) {
        int KC = Cin / 32;
        if (n >= 12000) {
            if (Cout == 128 && KC == 2) {
                int nblk = (n + 63) / 64;
                dim3 g(nblk), b(256);
                if (outbf16) conv_mfma_st<2, 2, 4, true ><<<g, b, 0, stream>>>(Xb, P, tab, Out, st, n, nblk);
                else         conv_mfma_st<2, 2, 4, false><<<g, b, 0, stream>>>(Xb, P, tab, Out, st, n, nblk);
                return;
            }
            if (Cout == 64 && KC == 2) {
                int nblk = (n + 127) / 128;   // RT=8 (acc=32 VGPR at T=1; halves B L2 traffic)
                dim3 g(nblk), b(256);
                if (outbf16) conv_mfma_st<1, 2, 8, true ><<<g, b, 0, stream>>>(Xb, P, tab, Out, st, n, nblk);
                else         conv_mfma_st<1, 2, 8, false><<<g, b, 0, stream>>>(Xb, P, tab, Out, st, n, nblk);
                return;
            }
            if (Cout == 128 && KC == 4) {
                int nblk = (n + 31) / 32;   // RT=2: 486 blocks
                dim3 g(nblk), b(256);
                if (outbf16) conv_mfma_st<2, 4, 2, true ><<<g, b, 0, stream>>>(Xb, P, tab, Out, st, n, nblk);
                else         conv_mfma_st<2, 4, 2, false><<<g, b, 0, stream>>>(Xb, P, tab, Out, st, n, nblk);
                return;
            }
        }
        int RB = (n >= 12000) ? 2 : 1;
        int nblk = (n + RB * 16 - 1) / (RB * 16);
        dim3 g(nblk), b(256);
        #define CONV_CASE(T_, RB_)                                                                        \
            if (Cout == 64 * T_ && RB == RB_) {                                                           \
                if (outbf16) conv_mfma<T_, RB_, true ><<<g, b, 0, stream>>>(Xb, P, tab, Out, n, Cin, KC, nblk); \
                else         conv_mfma<T_, RB_, false><<<g, b, 0, stream>>>(Xb, P, tab, Out, n, Cin, KC, nblk); \
                return;                                                                                   \
            }
        CONV_CASE(2, 2) CONV_CASE(2, 1)
        CONV_CASE(1, 2) CONV_CASE(1, 1)
        #undef CONV_CASE
    };
    auto bnapply = [&](void* X, const float* gb, int n, int C, bool bf16, int nrep) {
        bn_finalize<<<dim3(1), dim3(C), 0, stream>>>(stats, gb, scsh, C, 1.0f / n, nrep);
        if (bf16) {
            long tot8 = (long)n * C / 8;
            bn_apply_b16v<<<dim3((int)((tot8 + 255) / 256)), dim3(256), 0, stream>>>((unsigned short*)X, scsh, tot8, C);
        } else {
            long tot4 = (long)n * C / 4;
            bn_apply_f32v<<<dim3((int)((tot4 + 255) / 256)), dim3(256), 0, stream>>>((float*)X, scsh, tot4, C);
        }
    };
    auto bnelu = [&](void* X, const float* gb, int n, int C, bool bf16) {
        hipMemsetAsync(stats, 0, 2 * C * sizeof(float), stream);
        const int rpb = 512;
        if (bf16) bn_stats_k<true ><<<dim3((n + rpb - 1) / rpb), dim3(256), 0, stream>>>(X, stats, n, C, rpb);
        else      bn_stats_k<false><<<dim3((n + rpb - 1) / rpb), dim3(256), 0, stream>>>(X, stats, n, C, rpb);
        bnapply(X, gb, n, C, bf16, 1);
    };

    // ---- weight packs + input cast ----
    cast(feats2, f2bb, (long)N2 * 256);
    packW(w_out2, pc2, 27, 7, 3);
    packW(wt2,    pt2,  8, 7, 3);
    packW(wu2,    pg2, 27, 7, 2);
    packW(w_out1, pu1, 27, 7, 2);
    packW(wt1,    pt1,  8, 6, 2);
    packW(wu1,    pg1, 27, 6, 1);
    packW(w_out0, pu0, 27, 7, 1);

    // ---- level 2 ----
    buildTab(smallTab, m_c2, Mc2, N2);
    conv(f2bb, pc2, smallTab, out2, N2, 256, 128, false, nullptr);
    bnelu(out2, bn_out2, N2, 128, false);
    tconv_mfma<8, 2><<<dim3((N2 + 15) / 16), dim3(256), 0, stream>>>(f2bb, pt2, t2, N2);
    bnelu(t2, bn_up2a, G2n, 128, true);
    buildTab(smallTab, m_g2, Mg2, G2n);
    conv(t2, pg2, smallTab, t2c, G2n, 128, 128, true, nullptr);
    // t2c: stats+finalize only; affine+ELU fused into the scatter below
    hipMemsetAsync(stats, 0, 2 * 128 * sizeof(float), stream);
    bn_stats_k<true><<<dim3((G2n + 511) / 512), dim3(256), 0, stream>>>(t2c, stats, G2n, 128, 512);
    bn_finalize<<<dim3(1), dim3(128), 0, stream>>>(stats, bn_up2b, scsh, 128, 1.0f / G2n, 1);

    // ---- level 1 ----
    hipMemsetAsync(x1, 0, (size_t)U1 * 128 * sizeof(float), stream);
    {
        long tot4 = (long)N1 * 128 / 4;
        scatter_set_f32v<<<dim3((int)((tot4 + 255) / 256)), dim3(256), 0, stream>>>(x1, feats1, lat1, tot4, 32);
        long tot8 = (long)G2n * 128 / 8;
        scatter_bn_add_b16v<<<dim3((int)((tot8 + 255) / 256)), dim3(256), 0, stream>>>(x1, t2c, up1, scsh, tot8, 128);
    }
    cast(x1, x1b, (long)U1 * 128);
    buildTab(smallTab, m_u1, Mu1, U1);
    hipMemsetAsync(stats, 0, 8 * 2 * 128 * sizeof(float), stream);
    conv(x1b, pu1, smallTab, out1, U1, 128, 128, false, stats);
    bnapply(out1, bn_out1, U1, 128, false, 8);
    tconv_mfma<4, 1><<<dim3((U1 + 15) / 16), dim3(256), 0, stream>>>(x1b, pt1, t1, U1);
    bnelu(t1, bn_up1a, G1n, 64, true);
    buildTab(tab_g1, m_g1, Mg1, G1n);
    hipMemsetAsync(stats, 0, 8 * 2 * 64 * sizeof(float), stream);
    conv(t1, pg1, tab_g1, t1c, G1n, 64, 64, true, stats);
    // t1c: finalize only (stats fused in conv); affine+ELU fused into scatter
    bn_finalize<<<dim3(1), dim3(64), 0, stream>>>(stats, bn_up1b, scsh, 64, 1.0f / G1n, 8);

    // ---- level 0 ----
    hipMemsetAsync(x0, 0, (size_t)U0 * 64 * sizeof(float), stream);
    {
        long tot4 = (long)N0 * 64 / 4;
        scatter_set_f32v<<<dim3((int)((tot4 + 255) / 256)), dim3(256), 0, stream>>>(x0, feats0, lat0, tot4, 16);
        long tot8 = (long)G1n * 64 / 8;
        scatter_bn_add_b16v<<<dim3((int)((tot8 + 255) / 256)), dim3(256), 0, stream>>>(x0, t1c, up0, scsh, tot8, 64);
    }
    buildTab(tab_u0, m_u0, Mu0, U0);
    cast(x0, x0b, (long)U0 * 64);
    hipMemsetAsync(stats, 0, 8 * 2 * 128 * sizeof(float), stream);
    conv(x0b, pu0, tab_u0, out0, U0, 64, 128, false, stats);
    bnapply(out0, bn_out0, U0, 128, false, 8);
}